// Round 1
// baseline (4104.346 us; speedup 1.0000x reference)
//
#include <hip/hip_runtime.h>
#include <cstdint>
#include <cmath>

// Problem constants
static constexpr int BB = 16;    // batch
static constexpr int TT0 = 1024; // initial tokens
static constexpr int CC = 256;   // channels
static constexpr int EE = 512;   // embedding

// ---------------------------------------------------------------------------
// FPS: one block per batch, one thread per point (blockDim = Tt).
// Must match jax scan semantics exactly: idx[0]=0; dist computed in fp32 with
// ((dx*dx+dy*dy)+dz*dz) order, no FMA contraction; argmax first-index ties.
// ---------------------------------------------------------------------------
__global__ __launch_bounds__(1024) void fps_kernel(
    const float* __restrict__ ctr, int Tt, int Ksel, int* __restrict__ rep)
{
  int b = blockIdx.x;
  int tid = threadIdx.x;
  int lane = tid & 63, wid = tid >> 6, nw = (int)blockDim.x >> 6;
  const float* p = ctr + ((size_t)b * Tt + tid) * 3;
  float x = p[0], y = p[1], z = p[2];
  float d = INFINITY;
  __shared__ float scx, scy, scz;
  __shared__ int s_cur;
  __shared__ float wv[16];
  __shared__ int wi[16];
  if (tid == 0) { s_cur = 0; scx = x; scy = y; scz = z; }
  __syncthreads();
  for (int s = 0; s < Ksel; ++s) {
    if (tid == 0) rep[b * Ksel + s] = s_cur;
    float dx = __fsub_rn(x, scx);
    float dy = __fsub_rn(y, scy);
    float dz = __fsub_rn(z, scz);
    float dist = __fadd_rn(__fadd_rn(__fmul_rn(dx, dx), __fmul_rn(dy, dy)),
                           __fmul_rn(dz, dz));
    d = fminf(d, dist);
    float v = d; int ix = tid;
    #pragma unroll
    for (int off = 32; off > 0; off >>= 1) {
      float ov = __shfl_down(v, off);
      int oi = __shfl_down(ix, off);
      if (ov > v || (ov == v && oi < ix)) { v = ov; ix = oi; }
    }
    if (lane == 0) { wv[wid] = v; wi[wid] = ix; }
    __syncthreads();
    if (wid == 0) {
      float v2 = (lane < nw) ? wv[lane] : -INFINITY;
      int i2 = (lane < nw) ? wi[lane] : 0x7fffffff;
      #pragma unroll
      for (int off = 8; off > 0; off >>= 1) {
        float ov = __shfl_down(v2, off);
        int oi = __shfl_down(i2, off);
        if (ov > v2 || (ov == v2 && oi < i2)) { v2 = ov; i2 = oi; }
      }
      if (lane == 0) s_cur = i2;
    }
    __syncthreads();
    if (tid == s_cur) { scx = x; scy = y; scz = z; }
    __syncthreads();
  }
}

// ---------------------------------------------------------------------------
// kNN: one block (256 thr) per query row. d2 = (|q|^2 + |t|^2) - 2*dot,
// exact fp32 ops in reference order; k iterative argmin with first-index ties
// (== lax.top_k(-d2,k) order).
// ---------------------------------------------------------------------------
__global__ __launch_bounds__(256) void knn_kernel(
    const float* __restrict__ cq, const float* __restrict__ ct,
    int Tq, int Tt, int Kn, int* __restrict__ nn)
{
  int r = blockIdx.x;     // b*Tq + q
  int b = r / Tq;
  __shared__ float d2[1024];
  __shared__ float wv[4];
  __shared__ int wi[4];
  int tid = threadIdx.x, lane = tid & 63, wid = tid >> 6;
  float qx = cq[(size_t)r * 3 + 0];
  float qy = cq[(size_t)r * 3 + 1];
  float qz = cq[(size_t)r * 3 + 2];
  float sq = __fadd_rn(__fadd_rn(__fmul_rn(qx, qx), __fmul_rn(qy, qy)),
                       __fmul_rn(qz, qz));
  for (int t = tid; t < Tt; t += 256) {
    const float* tp = ct + ((size_t)b * Tt + t) * 3;
    float tx = tp[0], ty = tp[1], tz = tp[2];
    float st = __fadd_rn(__fadd_rn(__fmul_rn(tx, tx), __fmul_rn(ty, ty)),
                         __fmul_rn(tz, tz));
    float dot = __fadd_rn(__fadd_rn(__fmul_rn(qx, tx), __fmul_rn(qy, ty)),
                          __fmul_rn(qz, tz));
    d2[t] = __fsub_rn(__fadd_rn(sq, st), __fmul_rn(2.0f, dot));
  }
  __syncthreads();
  for (int j = 0; j < Kn; ++j) {
    float v = INFINITY; int ix = 0x7fffffff;
    for (int t = tid; t < Tt; t += 256) {
      float dv = d2[t];
      if (dv < v) { v = dv; ix = t; }
    }
    #pragma unroll
    for (int off = 32; off > 0; off >>= 1) {
      float ov = __shfl_down(v, off);
      int oi = __shfl_down(ix, off);
      if (ov < v || (ov == v && oi < ix)) { v = ov; ix = oi; }
    }
    if (lane == 0) { wv[wid] = v; wi[wid] = ix; }
    __syncthreads();
    if (tid == 0) {
      float bv = wv[0]; int bi = wi[0];
      for (int w = 1; w < 4; ++w)
        if (wv[w] < bv || (wv[w] == bv && wi[w] < bi)) { bv = wv[w]; bi = wi[w]; }
      nn[(size_t)r * Kn + j] = bi;
      d2[bi] = INFINITY;
    }
    __syncthreads();
  }
}

// ---------------------------------------------------------------------------
// Row gather: dst[b,q,:] = src[b, idx[b,q], :]
// ---------------------------------------------------------------------------
__global__ void gather_rows_kernel(
    const float* __restrict__ src, const int* __restrict__ idx,
    float* __restrict__ dst, int Tq, int Tt, int D, int total)
{
  int i = blockIdx.x * blockDim.x + threadIdx.x;
  if (i >= total) return;
  int d = i % D;
  int q = (i / D) % Tq;
  int b = i / (D * Tq);
  int s = idx[b * Tq + q];
  dst[i] = src[((size_t)b * Tt + s) * D + d];
}

// ---------------------------------------------------------------------------
// BatchNorm over rows (axis 0), C = 256 channels. Two logical inputs
// (concatenation) supported. Deterministic two-level reduction.
// ---------------------------------------------------------------------------
__global__ __launch_bounds__(256) void bn_stats_kernel(
    const float* __restrict__ x1, int R1, const float* __restrict__ x2, int R2,
    float* __restrict__ part, int nch)
{
  int c = threadIdx.x;
  int chunk = blockIdx.x;
  int R = R1 + R2;
  int per = (R + nch - 1) / nch;
  int r0 = chunk * per;
  int r1 = min(r0 + per, R);
  float s = 0.f, ss = 0.f;
  for (int r = r0; r < r1; ++r) {
    float v = (r < R1) ? x1[(size_t)r * 256 + c] : x2[(size_t)(r - R1) * 256 + c];
    s += v;
    ss = fmaf(v, v, ss);
  }
  part[(size_t)chunk * 512 + c] = s;
  part[(size_t)chunk * 512 + 256 + c] = ss;
}

__global__ __launch_bounds__(256) void bn_finalize_kernel(
    const float* __restrict__ part, int nch, int R,
    float* __restrict__ mean, float* __restrict__ rstd)
{
  int c = threadIdx.x;
  float s = 0.f, ss = 0.f;
  for (int k = 0; k < nch; ++k) {
    s += part[(size_t)k * 512 + c];
    ss += part[(size_t)k * 512 + 256 + c];
  }
  float m = s / (float)R;
  float v = ss / (float)R - m * m;
  if (v < 0.f) v = 0.f;
  mean[c] = m;
  rstd[c] = rsqrtf(v + 1e-5f);
}

__global__ void bn_apply_kernel(
    const float* __restrict__ x, float* __restrict__ y,
    const float* __restrict__ mean, const float* __restrict__ rstd,
    const float* __restrict__ g, const float* __restrict__ bta, int total)
{
  int i = blockIdx.x * blockDim.x + threadIdx.x;
  if (i >= total) return;
  int c = i & 255;
  y[i] = (x[i] - mean[c]) * rstd[c] * g[c] + bta[c];
}

// ---------------------------------------------------------------------------
// fp32 tiled GEMM: out = A(MxK) @ W(KxN) [+bias] [relu] [+resid]
// BM=BN=64, BK=16, 256 threads, 4x4 per thread.
// ---------------------------------------------------------------------------
__global__ __launch_bounds__(256) void gemm_kernel(
    const float* __restrict__ A, const float* __restrict__ W,
    const float* __restrict__ bias, const float* __restrict__ resid,
    float* __restrict__ out, int M, int N, int K, int relu)
{
  __shared__ float As[16][68];
  __shared__ float Bs[16][68];
  int bm = blockIdx.y * 64;
  int bn = blockIdx.x * 64;
  int tid = threadIdx.x;
  int tx = tid & 15, ty = tid >> 4;
  float acc[4][4] = {{0.f}};
  for (int k0 = 0; k0 < K; k0 += 16) {
    int kk = tid & 15;
    int r0 = tid >> 4;
    #pragma unroll
    for (int rr = 0; rr < 4; ++rr) {
      int row = bm + r0 + rr * 16;
      As[kk][r0 + rr * 16] = (row < M) ? A[(size_t)row * K + k0 + kk] : 0.f;
    }
    int col = tid & 63;
    int kq = tid >> 6;
    #pragma unroll
    for (int kk2 = 0; kk2 < 4; ++kk2) {
      Bs[kq + kk2 * 4][col] = W[(size_t)(k0 + kq + kk2 * 4) * N + bn + col];
    }
    __syncthreads();
    #pragma unroll
    for (int k = 0; k < 16; ++k) {
      float4 a = *(const float4*)&As[k][ty * 4];
      float4 b = *(const float4*)&Bs[k][tx * 4];
      float av[4] = {a.x, a.y, a.z, a.w};
      float bv[4] = {b.x, b.y, b.z, b.w};
      #pragma unroll
      for (int i = 0; i < 4; ++i)
        #pragma unroll
        for (int j = 0; j < 4; ++j)
          acc[i][j] = fmaf(av[i], bv[j], acc[i][j]);
    }
    __syncthreads();
  }
  #pragma unroll
  for (int i = 0; i < 4; ++i) {
    int m = bm + ty * 4 + i;
    if (m >= M) continue;
    #pragma unroll
    for (int j = 0; j < 4; ++j) {
      int n = bn + tx * 4 + j;
      float v = acc[i][j];
      if (bias) v += bias[n];
      if (relu) v = fmaxf(v, 0.f);
      if (resid) v += resid[(size_t)m * N + n];
      out[(size_t)m * N + n] = v;
    }
  }
}

// ---------------------------------------------------------------------------
// Fused per-query-row attention:
//   diff = Q[r] - K[nn_j]  (LDS, xor-swizzled float4 slots)
//   h    = relu(diff @ w1 + b1)  (per-thread channel, k accumulators)
//   s    = h @ w2 + b2
//   A    = softmax over j (per channel)
//   out  = sum_j A*V[nn_j] + skip
// ---------------------------------------------------------------------------
template <int KN>
__global__ __launch_bounds__(256) void attn_kernel(
    const float* __restrict__ Q, const float* __restrict__ KV,
    const int* __restrict__ nn, const float* __restrict__ w1,
    const float* __restrict__ b1, const float* __restrict__ w2,
    const float* __restrict__ b2, const float* __restrict__ skip,
    float* __restrict__ out, int Tq, int Tt)
{
  constexpr int J4 = KN / 4;
  constexpr int MASK = J4 - 1;
  __shared__ float4 dif4[256 * J4];
  __shared__ int nns[KN];
  int r = blockIdx.x;
  int b = r / Tq;
  int c = threadIdx.x;
  if (c < KN) nns[c] = nn[(size_t)r * KN + c];
  __syncthreads();
  float qv = Q[(size_t)r * 256 + c];
  const float* kvb = KV + (size_t)b * Tt * 512;
  #pragma unroll
  for (int j4 = 0; j4 < J4; ++j4) {
    float4 t;
    t.x = qv - kvb[(size_t)nns[j4 * 4 + 0] * 512 + c];
    t.y = qv - kvb[(size_t)nns[j4 * 4 + 1] * 512 + c];
    t.z = qv - kvb[(size_t)nns[j4 * 4 + 2] * 512 + c];
    t.w = qv - kvb[(size_t)nns[j4 * 4 + 3] * 512 + c];
    dif4[c * J4 + (j4 ^ (c & MASK))] = t;
  }
  __syncthreads();

  float acc[KN];
  {
    float bb = b1[c];
    #pragma unroll
    for (int j = 0; j < KN; ++j) acc[j] = bb;
  }
  for (int d = 0; d < 256; ++d) {
    float w = w1[d * 256 + c];
    int base = d * J4;
    int key = d & MASK;
    #pragma unroll
    for (int j4 = 0; j4 < J4; ++j4) {
      float4 v = dif4[base + (j4 ^ key)];
      acc[j4 * 4 + 0] = fmaf(v.x, w, acc[j4 * 4 + 0]);
      acc[j4 * 4 + 1] = fmaf(v.y, w, acc[j4 * 4 + 1]);
      acc[j4 * 4 + 2] = fmaf(v.z, w, acc[j4 * 4 + 2]);
      acc[j4 * 4 + 3] = fmaf(v.w, w, acc[j4 * 4 + 3]);
    }
  }
  #pragma unroll
  for (int j = 0; j < KN; ++j) acc[j] = fmaxf(acc[j], 0.f);
  __syncthreads();
  #pragma unroll
  for (int j4 = 0; j4 < J4; ++j4) {
    dif4[c * J4 + (j4 ^ (c & MASK))] =
        make_float4(acc[j4 * 4 + 0], acc[j4 * 4 + 1], acc[j4 * 4 + 2], acc[j4 * 4 + 3]);
  }
  __syncthreads();
  {
    float bb = b2[c];
    #pragma unroll
    for (int j = 0; j < KN; ++j) acc[j] = bb;
  }
  for (int d = 0; d < 256; ++d) {
    float w = w2[d * 256 + c];
    int base = d * J4;
    int key = d & MASK;
    #pragma unroll
    for (int j4 = 0; j4 < J4; ++j4) {
      float4 v = dif4[base + (j4 ^ key)];
      acc[j4 * 4 + 0] = fmaf(v.x, w, acc[j4 * 4 + 0]);
      acc[j4 * 4 + 1] = fmaf(v.y, w, acc[j4 * 4 + 1]);
      acc[j4 * 4 + 2] = fmaf(v.z, w, acc[j4 * 4 + 2]);
      acc[j4 * 4 + 3] = fmaf(v.w, w, acc[j4 * 4 + 3]);
    }
  }
  // softmax over j (per channel)
  float m = acc[0];
  #pragma unroll
  for (int j = 1; j < KN; ++j) m = fmaxf(m, acc[j]);
  float sum = 0.f;
  #pragma unroll
  for (int j = 0; j < KN; ++j) {
    float e = expf(acc[j] - m);
    acc[j] = e;
    sum += e;
  }
  float inv = 1.0f / sum;
  float o = 0.f;
  #pragma unroll
  for (int j = 0; j < KN; ++j) {
    float vv = kvb[(size_t)nns[j] * 512 + 256 + c];
    o = fmaf(acc[j] * inv, vv, o);
  }
  out[(size_t)r * 256 + c] = o + skip[(size_t)r * 256 + c];
}

// ---------------------------------------------------------------------------
// Final head
// ---------------------------------------------------------------------------
__global__ void gmean_kernel(const float* __restrict__ tok,
                             float* __restrict__ out, int Tt)
{
  int i = blockIdx.x * blockDim.x + threadIdx.x;
  if (i >= BB * CC) return;
  int b = i >> 8;
  int c = i & 255;
  float s = 0.f;
  for (int t = 0; t < Tt; ++t) s += tok[((size_t)b * Tt + t) * 256 + c];
  out[i] = s / (float)Tt;
}

__global__ void embbn_kernel(const float* __restrict__ x,
                             const float* __restrict__ g,
                             const float* __restrict__ bta,
                             float* __restrict__ y)
{
  int e = blockIdx.x * blockDim.x + threadIdx.x;
  if (e >= EE) return;
  float s = 0.f;
  for (int r = 0; r < BB; ++r) s += x[r * EE + e];
  float m = s / (float)BB;
  float vs = 0.f;
  for (int r = 0; r < BB; ++r) {
    float d = x[r * EE + e] - m;
    vs = fmaf(d, d, vs);
  }
  float rs = rsqrtf(vs / (float)BB + 1e-5f);
  for (int r = 0; r < BB; ++r) {
    float val = (x[r * EE + e] - m) * rs * g[e] + bta[e];
    y[r * EE + e] = fmaxf(val, 0.f);
  }
}

__global__ __launch_bounds__(256) void topk_norm_kernel(
    const float* __restrict__ gin, float* __restrict__ out)
{
  int b = blockIdx.x, tid = threadIdx.x, lane = tid & 63, wid = tid >> 6;
  __shared__ float vals[512];
  __shared__ float wv[4];
  __shared__ int wi[4];
  __shared__ float sh;
  float g0 = gin[b * 512 + tid];
  float g1 = gin[b * 512 + 256 + tid];
  vals[tid] = g0;
  vals[256 + tid] = g1;
  __syncthreads();
  for (int it = 0; it < 64; ++it) {
    float v = vals[tid];
    int ix = tid;
    float u = vals[256 + tid];
    if (u > v) { v = u; ix = 256 + tid; }
    #pragma unroll
    for (int off = 32; off > 0; off >>= 1) {
      float ov = __shfl_down(v, off);
      int oi = __shfl_down(ix, off);
      if (ov > v || (ov == v && oi < ix)) { v = ov; ix = oi; }
    }
    if (lane == 0) { wv[wid] = v; wi[wid] = ix; }
    __syncthreads();
    if (tid == 0) {
      float bv = wv[0]; int bi = wi[0];
      for (int w = 1; w < 4; ++w)
        if (wv[w] > bv || (wv[w] == bv && wi[w] < bi)) { bv = wv[w]; bi = wi[w]; }
      vals[bi] = -INFINITY;
      sh = bv;
    }
    __syncthreads();
  }
  float thr = sh;
  float m0 = (g0 >= thr) ? g0 : 0.f;
  float m1 = (g1 >= thr) ? g1 : 0.f;
  float ss = m0 * m0 + m1 * m1;
  #pragma unroll
  for (int off = 32; off > 0; off >>= 1) ss += __shfl_down(ss, off);
  if (lane == 0) wv[wid] = ss;
  __syncthreads();
  if (tid == 0) {
    float t = wv[0] + wv[1] + wv[2] + wv[3];
    sh = fmaxf(sqrtf(t), 1e-12f);
  }
  __syncthreads();
  float n = sh;
  out[b * 512 + tid] = m0 / n;
  out[b * 512 + 256 + tid] = m1 / n;
}

// ---------------------------------------------------------------------------
// Host orchestration
// ---------------------------------------------------------------------------
extern "C" void kernel_launch(void* const* d_in, const int* in_sizes, int n_in,
                              void* d_out, int out_size, void* d_ws, size_t ws_size,
                              hipStream_t stream)
{
  const float* tokens  = (const float*)d_in[0];
  const float* centers = (const float*)d_in[1];
  // d_in[2] = lrfs: dead in the reference (gathered, never consumed)
  const float* wq      = (const float*)d_in[3];
  const float* wkv     = (const float*)d_in[4];
  const float* mlp_w1  = (const float*)d_in[5];
  const float* mlp_b1  = (const float*)d_in[6];
  const float* mlp_w2  = (const float*)d_in[7];
  const float* mlp_b2  = (const float*)d_in[8];
  const float* bn1_g   = (const float*)d_in[9];
  const float* bn1_b   = (const float*)d_in[10];
  const float* bn2_g   = (const float*)d_in[11];
  const float* bn2_b   = (const float*)d_in[12];
  const float* att_w1  = (const float*)d_in[13];
  const float* att_b1  = (const float*)d_in[14];
  const float* att_w2  = (const float*)d_in[15];
  const float* att_b2  = (const float*)d_in[16];
  const float* emb_w   = (const float*)d_in[17];
  const float* emb_b   = (const float*)d_in[18];
  const float* embn_g  = (const float*)d_in[19];
  const float* embn_b  = (const float*)d_in[20];
  (void)in_sizes; (void)n_in; (void)out_size; (void)ws_size;

  char* ws = (char*)d_ws;
  size_t off = 0;
  auto alloc = [&](size_t bytes) -> void* {
    void* p = ws + off;
    off += (bytes + 255) & ~(size_t)255;
    return p;
  };
  const size_t tokMax = (size_t)BB * 512 * CC * 4;
  float* tokA     = (float*)alloc(tokMax);
  float* tokB     = (float*)alloc(tokMax);
  float* ctrA     = (float*)alloc((size_t)BB * 512 * 3 * 4);
  float* ctrB     = (float*)alloc((size_t)BB * 512 * 3 * 4);
  float* tokq_raw = (float*)alloc(tokMax);
  float* tokq_bn  = (float*)alloc(tokMax);
  float* tokt_bn  = (float*)alloc(tokMax);
  float* Qb       = (float*)alloc(tokMax);
  float* KVb      = (float*)alloc((size_t)BB * 1024 * 512 * 4);
  float* tq1      = (float*)alloc(tokMax);
  float* tqbn     = (float*)alloc(tokMax);
  float* mlph     = (float*)alloc((size_t)BB * 512 * 512 * 4);
  int*   rep      = (int*)alloc((size_t)BB * 512 * 4);
  int*   nnb      = (int*)alloc((size_t)BB * 512 * 64 * 4);
  float* bnpart   = (float*)alloc((size_t)64 * 512 * 4);
  float* bnmean   = (float*)alloc(256 * 4);
  float* bnrstd   = (float*)alloc(256 * 4);
  float* gmeanb   = (float*)alloc((size_t)BB * CC * 4);
  float* gembb    = (float*)alloc((size_t)BB * EE * 4);
  float* grelub   = (float*)alloc((size_t)BB * EE * 4);

  const int NC[3] = {512, 256, 128};
  const int NN[3] = {16, 32, 64};

  const float* cur_tok = tokens;
  const float* cur_ctr = centers;
  int curTt = TT0;

  float* tok_bufs[2] = {tokA, tokB};
  float* ctr_bufs[2] = {ctrA, ctrB};

  for (int i = 0; i < 3; ++i) {
    int Tq = NC[i], Kn = NN[i], Tt = curTt;
    float* ctr_q = ctr_bufs[i & 1];
    float* tok_next = tok_bufs[i & 1];
    int M = BB * Tq;

    // FPS + gathers + kNN
    fps_kernel<<<BB, Tt, 0, stream>>>(cur_ctr, Tt, Tq, rep);
    {
      int tot = BB * Tq * 3;
      gather_rows_kernel<<<(tot + 255) / 256, 256, 0, stream>>>(
          cur_ctr, rep, ctr_q, Tq, Tt, 3, tot);
    }
    {
      int tot = M * CC;
      gather_rows_kernel<<<(tot + 255) / 256, 256, 0, stream>>>(
          cur_tok, rep, tokq_raw, Tq, Tt, CC, tot);
    }
    knn_kernel<<<M, 256, 0, stream>>>(ctr_q, cur_ctr, Tq, Tt, Kn, nnb);

    // Optional BN1 over concat(query, target)
    const float* q_src;
    const float* t_src;
    if (i == 0) {
      q_src = tokq_raw;
      t_src = cur_tok;
    } else {
      int R1 = M, R2 = BB * Tt;
      bn_stats_kernel<<<64, 256, 0, stream>>>(tokq_raw, R1, cur_tok, R2, bnpart, 64);
      bn_finalize_kernel<<<1, 256, 0, stream>>>(bnpart, 64, R1 + R2, bnmean, bnrstd);
      {
        int tot = R1 * CC;
        bn_apply_kernel<<<(tot + 255) / 256, 256, 0, stream>>>(
            tokq_raw, tokq_bn, bnmean, bnrstd, bn1_g + i * CC, bn1_b + i * CC, tot);
      }
      {
        int tot = R2 * CC;
        bn_apply_kernel<<<(tot + 255) / 256, 256, 0, stream>>>(
            cur_tok, tokt_bn, bnmean, bnrstd, bn1_g + i * CC, bn1_b + i * CC, tot);
      }
      q_src = tokq_bn;
      t_src = tokt_bn;
    }

    // Q and KV projections
    gemm_kernel<<<dim3(CC / 64, (M + 63) / 64), 256, 0, stream>>>(
        q_src, wq + (size_t)i * CC * CC, nullptr, nullptr, Qb, M, CC, CC, 0);
    gemm_kernel<<<dim3(512 / 64, (BB * Tt + 63) / 64), 256, 0, stream>>>(
        t_src, wkv + (size_t)i * CC * 512, nullptr, nullptr, KVb, BB * Tt, 512, CC, 0);

    // Fused neighborhood attention (+ skip)
    if (Kn == 16)
      attn_kernel<16><<<M, 256, 0, stream>>>(Qb, KVb, nnb,
          att_w1 + (size_t)i * CC * CC, att_b1 + i * CC,
          att_w2 + (size_t)i * CC * CC, att_b2 + i * CC, tokq_raw, tq1, Tq, Tt);
    else if (Kn == 32)
      attn_kernel<32><<<M, 256, 0, stream>>>(Qb, KVb, nnb,
          att_w1 + (size_t)i * CC * CC, att_b1 + i * CC,
          att_w2 + (size_t)i * CC * CC, att_b2 + i * CC, tokq_raw, tq1, Tq, Tt);
    else
      attn_kernel<64><<<M, 256, 0, stream>>>(Qb, KVb, nnb,
          att_w1 + (size_t)i * CC * CC, att_b1 + i * CC,
          att_w2 + (size_t)i * CC * CC, att_b2 + i * CC, tokq_raw, tq1, Tq, Tt);

    // BN2 + MLP (+ skip2)
    bn_stats_kernel<<<64, 256, 0, stream>>>(tq1, M, tq1, 0, bnpart, 64);
    bn_finalize_kernel<<<1, 256, 0, stream>>>(bnpart, 64, M, bnmean, bnrstd);
    {
      int tot = M * CC;
      bn_apply_kernel<<<(tot + 255) / 256, 256, 0, stream>>>(
          tq1, tqbn, bnmean, bnrstd, bn2_g + i * CC, bn2_b + i * CC, tot);
    }
    gemm_kernel<<<dim3(512 / 64, (M + 63) / 64), 256, 0, stream>>>(
        tqbn, mlp_w1 + (size_t)i * CC * 512, mlp_b1 + i * 512, nullptr,
        mlph, M, 512, CC, 1);
    gemm_kernel<<<dim3(CC / 64, (M + 63) / 64), 256, 0, stream>>>(
        mlph, mlp_w2 + (size_t)i * 512 * CC, mlp_b2 + i * CC, tq1,
        tok_next, M, CC, 512, 0);

    cur_tok = tok_next;
    cur_ctr = ctr_q;
    curTt = Tq;
  }

  // Final head: mean -> emb GEMM -> BN+relu -> top64 threshold -> L2 normalize
  gmean_kernel<<<(BB * CC + 255) / 256, 256, 0, stream>>>(cur_tok, gmeanb, curTt);
  gemm_kernel<<<dim3(EE / 64, 1), 256, 0, stream>>>(
      gmeanb, emb_w, emb_b, nullptr, gembb, BB, EE, CC, 0);
  embbn_kernel<<<2, 256, 0, stream>>>(gembb, embn_g, embn_b, grelub);
  topk_norm_kernel<<<BB, 256, 0, stream>>>(grelub, (float*)d_out);
}

// Round 2
// 3139.788 us; speedup vs baseline: 1.3072x; 1.3072x over previous
//
#include <hip/hip_runtime.h>
#include <cstdint>
#include <cmath>

// Problem constants
static constexpr int BB = 16;    // batch
static constexpr int TT0 = 1024; // initial tokens
static constexpr int CC = 256;   // channels
static constexpr int EE = 512;   // embedding

// ---------------------------------------------------------------------------
// FPS: one block per batch, one thread per point (blockDim = Tt).
// Must match jax scan semantics exactly: idx[0]=0; dist computed in fp32 with
// ((dx*dx+dy*dy)+dz*dz) order, no FMA contraction; argmax first-index ties.
// ---------------------------------------------------------------------------
__global__ __launch_bounds__(1024) void fps_kernel(
    const float* __restrict__ ctr, int Tt, int Ksel, int* __restrict__ rep)
{
  int b = blockIdx.x;
  int tid = threadIdx.x;
  int lane = tid & 63, wid = tid >> 6, nw = (int)blockDim.x >> 6;
  const float* p = ctr + ((size_t)b * Tt + tid) * 3;
  float x = p[0], y = p[1], z = p[2];
  float d = INFINITY;
  __shared__ float scx, scy, scz;
  __shared__ int s_cur;
  __shared__ float wv[16];
  __shared__ int wi[16];
  if (tid == 0) { s_cur = 0; scx = x; scy = y; scz = z; }
  __syncthreads();
  for (int s = 0; s < Ksel; ++s) {
    if (tid == 0) rep[b * Ksel + s] = s_cur;
    float dx = __fsub_rn(x, scx);
    float dy = __fsub_rn(y, scy);
    float dz = __fsub_rn(z, scz);
    float dist = __fadd_rn(__fadd_rn(__fmul_rn(dx, dx), __fmul_rn(dy, dy)),
                           __fmul_rn(dz, dz));
    d = fminf(d, dist);
    float v = d; int ix = tid;
    #pragma unroll
    for (int off = 32; off > 0; off >>= 1) {
      float ov = __shfl_down(v, off);
      int oi = __shfl_down(ix, off);
      if (ov > v || (ov == v && oi < ix)) { v = ov; ix = oi; }
    }
    if (lane == 0) { wv[wid] = v; wi[wid] = ix; }
    __syncthreads();
    if (wid == 0) {
      float v2 = (lane < nw) ? wv[lane] : -INFINITY;
      int i2 = (lane < nw) ? wi[lane] : 0x7fffffff;
      #pragma unroll
      for (int off = 8; off > 0; off >>= 1) {
        float ov = __shfl_down(v2, off);
        int oi = __shfl_down(i2, off);
        if (ov > v2 || (ov == v2 && oi < i2)) { v2 = ov; i2 = oi; }
      }
      if (lane == 0) s_cur = i2;
    }
    __syncthreads();
    if (tid == s_cur) { scx = x; scy = y; scz = z; }
    __syncthreads();
  }
}

// ---------------------------------------------------------------------------
// kNN: one block (256 thr) per query row. Exact fp32 ops in reference order;
// k iterative argmin with first-index ties (== lax.top_k(-d2,k) order).
// ---------------------------------------------------------------------------
__global__ __launch_bounds__(256) void knn_kernel(
    const float* __restrict__ cq, const float* __restrict__ ct,
    int Tq, int Tt, int Kn, int* __restrict__ nn)
{
  int r = blockIdx.x;     // b*Tq + q
  int b = r / Tq;
  __shared__ float d2[1024];
  __shared__ float wv[4];
  __shared__ int wi[4];
  int tid = threadIdx.x, lane = tid & 63, wid = tid >> 6;
  float qx = cq[(size_t)r * 3 + 0];
  float qy = cq[(size_t)r * 3 + 1];
  float qz = cq[(size_t)r * 3 + 2];
  float sq = __fadd_rn(__fadd_rn(__fmul_rn(qx, qx), __fmul_rn(qy, qy)),
                       __fmul_rn(qz, qz));
  for (int t = tid; t < Tt; t += 256) {
    const float* tp = ct + ((size_t)b * Tt + t) * 3;
    float tx = tp[0], ty = tp[1], tz = tp[2];
    float st = __fadd_rn(__fadd_rn(__fmul_rn(tx, tx), __fmul_rn(ty, ty)),
                         __fmul_rn(tz, tz));
    float dot = __fadd_rn(__fadd_rn(__fmul_rn(qx, tx), __fmul_rn(qy, ty)),
                          __fmul_rn(qz, tz));
    d2[t] = __fsub_rn(__fadd_rn(sq, st), __fmul_rn(2.0f, dot));
  }
  __syncthreads();
  for (int j = 0; j < Kn; ++j) {
    float v = INFINITY; int ix = 0x7fffffff;
    for (int t = tid; t < Tt; t += 256) {
      float dv = d2[t];
      if (dv < v) { v = dv; ix = t; }
    }
    #pragma unroll
    for (int off = 32; off > 0; off >>= 1) {
      float ov = __shfl_down(v, off);
      int oi = __shfl_down(ix, off);
      if (ov < v || (ov == v && oi < ix)) { v = ov; ix = oi; }
    }
    if (lane == 0) { wv[wid] = v; wi[wid] = ix; }
    __syncthreads();
    if (tid == 0) {
      float bv = wv[0]; int bi = wi[0];
      for (int w = 1; w < 4; ++w)
        if (wv[w] < bv || (wv[w] == bv && wi[w] < bi)) { bv = wv[w]; bi = wi[w]; }
      nn[(size_t)r * Kn + j] = bi;
      d2[bi] = INFINITY;
    }
    __syncthreads();
  }
}

// ---------------------------------------------------------------------------
// Row gather: dst[b,q,:] = src[b, idx[b,q], :]
// ---------------------------------------------------------------------------
__global__ void gather_rows_kernel(
    const float* __restrict__ src, const int* __restrict__ idx,
    float* __restrict__ dst, int Tq, int Tt, int D, int total)
{
  int i = blockIdx.x * blockDim.x + threadIdx.x;
  if (i >= total) return;
  int d = i % D;
  int q = (i / D) % Tq;
  int b = i / (D * Tq);
  int s = idx[b * Tq + q];
  dst[i] = src[((size_t)b * Tt + s) * D + d];
}

// ---------------------------------------------------------------------------
// BatchNorm over rows (axis 0), C = 256 channels.
// ---------------------------------------------------------------------------
__global__ __launch_bounds__(256) void bn_stats_kernel(
    const float* __restrict__ x1, int R1, const float* __restrict__ x2, int R2,
    float* __restrict__ part, int nch)
{
  int c = threadIdx.x;
  int chunk = blockIdx.x;
  int R = R1 + R2;
  int per = (R + nch - 1) / nch;
  int r0 = chunk * per;
  int r1 = min(r0 + per, R);
  float s = 0.f, ss = 0.f;
  for (int r = r0; r < r1; ++r) {
    float v = (r < R1) ? x1[(size_t)r * 256 + c] : x2[(size_t)(r - R1) * 256 + c];
    s += v;
    ss = fmaf(v, v, ss);
  }
  part[(size_t)chunk * 512 + c] = s;
  part[(size_t)chunk * 512 + 256 + c] = ss;
}

__global__ __launch_bounds__(256) void bn_finalize_kernel(
    const float* __restrict__ part, int nch, int R,
    float* __restrict__ mean, float* __restrict__ rstd)
{
  int c = threadIdx.x;
  float s = 0.f, ss = 0.f;
  for (int k = 0; k < nch; ++k) {
    s += part[(size_t)k * 512 + c];
    ss += part[(size_t)k * 512 + 256 + c];
  }
  float m = s / (float)R;
  float v = ss / (float)R - m * m;
  if (v < 0.f) v = 0.f;
  mean[c] = m;
  rstd[c] = rsqrtf(v + 1e-5f);
}

__global__ void bn_apply_kernel(
    const float* __restrict__ x, float* __restrict__ y,
    const float* __restrict__ mean, const float* __restrict__ rstd,
    const float* __restrict__ g, const float* __restrict__ bta, int total)
{
  int i = blockIdx.x * blockDim.x + threadIdx.x;
  if (i >= total) return;
  int c = i & 255;
  y[i] = (x[i] - mean[c]) * rstd[c] * g[c] + bta[c];
}

// ---------------------------------------------------------------------------
// fp32 tiled GEMM: out = A(MxK, row stride lda) @ W(KxN, row stride ldw)
//                  [+bias] [relu] [+resid]
// BM=BN=64, BK=32, 256 threads, 4x4 per thread, float4 global loads.
// Requires: K%32==0, N%64==0, lda%4==0, ldw==row stride of W.
// ---------------------------------------------------------------------------
__global__ __launch_bounds__(256) void gemm_kernel(
    const float* __restrict__ A, int lda,
    const float* __restrict__ W, int ldw,
    const float* __restrict__ bias, const float* __restrict__ resid,
    float* __restrict__ out, int M, int N, int K, int relu)
{
  __shared__ float As[32][68];
  __shared__ float Bs[32][68];
  int bm = blockIdx.y * 64;
  int bn = blockIdx.x * 64;
  int tid = threadIdx.x;
  int tx = tid & 15, ty = tid >> 4;
  int arow = tid >> 3;          // 0..31
  int ak = (tid & 7) * 4;       // 0,4,...,28
  int wk = tid >> 4;            // 0..15
  int wn = (tid & 15) * 4;      // 0..60
  float acc[4][4] = {{0.f}};
  for (int k0 = 0; k0 < K; k0 += 32) {
    #pragma unroll
    for (int h = 0; h < 2; ++h) {
      int row = bm + arow + h * 32;
      float4 a = (row < M)
          ? *(const float4*)&A[(size_t)row * lda + k0 + ak]
          : make_float4(0.f, 0.f, 0.f, 0.f);
      As[ak + 0][arow + h * 32] = a.x;
      As[ak + 1][arow + h * 32] = a.y;
      As[ak + 2][arow + h * 32] = a.z;
      As[ak + 3][arow + h * 32] = a.w;
    }
    #pragma unroll
    for (int h = 0; h < 2; ++h) {
      int krow = k0 + wk + h * 16;
      *(float4*)&Bs[wk + h * 16][wn] =
          *(const float4*)&W[(size_t)krow * ldw + bn + wn];
    }
    __syncthreads();
    #pragma unroll
    for (int k = 0; k < 32; ++k) {
      float4 a = *(const float4*)&As[k][ty * 4];
      float4 b = *(const float4*)&Bs[k][tx * 4];
      float av[4] = {a.x, a.y, a.z, a.w};
      float bv[4] = {b.x, b.y, b.z, b.w};
      #pragma unroll
      for (int i = 0; i < 4; ++i)
        #pragma unroll
        for (int j = 0; j < 4; ++j)
          acc[i][j] = fmaf(av[i], bv[j], acc[i][j]);
    }
    __syncthreads();
  }
  #pragma unroll
  for (int i = 0; i < 4; ++i) {
    int m = bm + ty * 4 + i;
    if (m >= M) continue;
    #pragma unroll
    for (int j = 0; j < 4; ++j) {
      int n = bn + tx * 4 + j;
      float v = acc[i][j];
      if (bias) v += bias[n];
      if (relu) v = fmaxf(v, 0.f);
      if (resid) v += resid[(size_t)m * N + n];
      out[(size_t)m * N + n] = v;
    }
  }
}

// ---------------------------------------------------------------------------
// Fused per-query-row attention, restructured:
//   h_j[c] = relu(Qw[r][c] - Kw[nn_j][c] + b1[c])     (Qw=Q@w1, Kw=Kf@w1)
//   sim_j  = h_j @ w2 + b2      (single GEMV pass, h staged in LDS)
//   A      = softmax over j (online across j-groups of <=32)
//   out    = sum_j A*V[nn_j] + skip
// LDS <= 32KB (j-group), XOR-swizzled float4 slots, broadcast reads.
// ---------------------------------------------------------------------------
template <int KN>
__global__ __launch_bounds__(256) void attn2_kernel(
    const float* __restrict__ Qw, const float* __restrict__ Kw,
    const float* __restrict__ Vb, const int* __restrict__ nn,
    const float* __restrict__ b1, const float* __restrict__ w2,
    const float* __restrict__ b2, const float* __restrict__ skip,
    float* __restrict__ out, int Tq, int Tt)
{
  constexpr int JG = (KN < 32) ? KN : 32;   // j-group size
  constexpr int NG = KN / JG;
  constexpr int J4 = JG / 4;
  constexpr int MASK = J4 - 1;
  __shared__ float4 h4[256 * J4];
  __shared__ int nns[KN];
  int q = blockIdx.x, b = blockIdx.y;
  int r = b * Tq + q;
  int c = threadIdx.x;
  if (c < KN) nns[c] = nn[(size_t)r * KN + c];
  __syncthreads();
  float qw = Qw[(size_t)r * 256 + c];
  float bb1 = b1[c];
  float bb2 = b2[c];
  const float* kwb = Kw + (size_t)b * Tt * 256;
  const float* vbb = Vb + (size_t)b * Tt * 256;
  float m = -INFINITY, ssum = 0.f, o = 0.f;
  #pragma unroll
  for (int g = 0; g < NG; ++g) {
    if (g) __syncthreads();   // prior group's LDS reads must finish
    #pragma unroll
    for (int j4 = 0; j4 < J4; ++j4) {
      float4 t;
      t.x = fmaxf(qw - kwb[(size_t)nns[g * JG + j4 * 4 + 0] * 256 + c] + bb1, 0.f);
      t.y = fmaxf(qw - kwb[(size_t)nns[g * JG + j4 * 4 + 1] * 256 + c] + bb1, 0.f);
      t.z = fmaxf(qw - kwb[(size_t)nns[g * JG + j4 * 4 + 2] * 256 + c] + bb1, 0.f);
      t.w = fmaxf(qw - kwb[(size_t)nns[g * JG + j4 * 4 + 3] * 256 + c] + bb1, 0.f);
      h4[c * J4 + (j4 ^ (c & MASK))] = t;
    }
    __syncthreads();
    float acc[JG];
    #pragma unroll
    for (int j = 0; j < JG; ++j) acc[j] = bb2;
    const float* wp = w2 + c;
    #pragma unroll 4
    for (int d = 0; d < 256; ++d) {
      float w = wp[d * 256];
      int base = d * J4;
      int key = d & MASK;
      #pragma unroll
      for (int j4 = 0; j4 < J4; ++j4) {
        float4 v = h4[base + (j4 ^ key)];
        acc[j4 * 4 + 0] = fmaf(v.x, w, acc[j4 * 4 + 0]);
        acc[j4 * 4 + 1] = fmaf(v.y, w, acc[j4 * 4 + 1]);
        acc[j4 * 4 + 2] = fmaf(v.z, w, acc[j4 * 4 + 2]);
        acc[j4 * 4 + 3] = fmaf(v.w, w, acc[j4 * 4 + 3]);
      }
    }
    // online softmax update across groups
    float gm = acc[0];
    #pragma unroll
    for (int j = 1; j < JG; ++j) gm = fmaxf(gm, acc[j]);
    if (gm > m) {
      float sc = expf(m - gm);   // m==-inf on first group -> 0
      ssum *= sc;
      o *= sc;
      m = gm;
    }
    #pragma unroll
    for (int j = 0; j < JG; ++j) {
      float e = expf(acc[j] - m);
      ssum += e;
      float vv = vbb[(size_t)nns[g * JG + j] * 256 + c];
      o = fmaf(e, vv, o);
    }
  }
  out[(size_t)r * 256 + c] = o / ssum + skip[(size_t)r * 256 + c];
}

// ---------------------------------------------------------------------------
// Final head
// ---------------------------------------------------------------------------
__global__ void gmean_kernel(const float* __restrict__ tok,
                             float* __restrict__ out, int Tt)
{
  int i = blockIdx.x * blockDim.x + threadIdx.x;
  if (i >= BB * CC) return;
  int b = i >> 8;
  int c = i & 255;
  float s = 0.f;
  for (int t = 0; t < Tt; ++t) s += tok[((size_t)b * Tt + t) * 256 + c];
  out[i] = s / (float)Tt;
}

__global__ void embbn_kernel(const float* __restrict__ x,
                             const float* __restrict__ g,
                             const float* __restrict__ bta,
                             float* __restrict__ y)
{
  int e = blockIdx.x * blockDim.x + threadIdx.x;
  if (e >= EE) return;
  float s = 0.f;
  for (int r = 0; r < BB; ++r) s += x[r * EE + e];
  float m = s / (float)BB;
  float vs = 0.f;
  for (int r = 0; r < BB; ++r) {
    float d = x[r * EE + e] - m;
    vs = fmaf(d, d, vs);
  }
  float rs = rsqrtf(vs / (float)BB + 1e-5f);
  for (int r = 0; r < BB; ++r) {
    float val = (x[r * EE + e] - m) * rs * g[e] + bta[e];
    y[r * EE + e] = fmaxf(val, 0.f);
  }
}

__global__ __launch_bounds__(256) void topk_norm_kernel(
    const float* __restrict__ gin, float* __restrict__ out)
{
  int b = blockIdx.x, tid = threadIdx.x, lane = tid & 63, wid = tid >> 6;
  __shared__ float vals[512];
  __shared__ float wv[4];
  __shared__ int wi[4];
  __shared__ float sh;
  float g0 = gin[b * 512 + tid];
  float g1 = gin[b * 512 + 256 + tid];
  vals[tid] = g0;
  vals[256 + tid] = g1;
  __syncthreads();
  for (int it = 0; it < 64; ++it) {
    float v = vals[tid];
    int ix = tid;
    float u = vals[256 + tid];
    if (u > v) { v = u; ix = 256 + tid; }
    #pragma unroll
    for (int off = 32; off > 0; off >>= 1) {
      float ov = __shfl_down(v, off);
      int oi = __shfl_down(ix, off);
      if (ov > v || (ov == v && oi < ix)) { v = ov; ix = oi; }
    }
    if (lane == 0) { wv[wid] = v; wi[wid] = ix; }
    __syncthreads();
    if (tid == 0) {
      float bv = wv[0]; int bi = wi[0];
      for (int w = 1; w < 4; ++w)
        if (wv[w] > bv || (wv[w] == bv && wi[w] < bi)) { bv = wv[w]; bi = wi[w]; }
      vals[bi] = -INFINITY;
      sh = bv;
    }
    __syncthreads();
  }
  float thr = sh;
  float m0 = (g0 >= thr) ? g0 : 0.f;
  float m1 = (g1 >= thr) ? g1 : 0.f;
  float ss = m0 * m0 + m1 * m1;
  #pragma unroll
  for (int off = 32; off > 0; off >>= 1) ss += __shfl_down(ss, off);
  if (lane == 0) wv[wid] = ss;
  __syncthreads();
  if (tid == 0) {
    float t = wv[0] + wv[1] + wv[2] + wv[3];
    sh = fmaxf(sqrtf(t), 1e-12f);
  }
  __syncthreads();
  float n = sh;
  out[b * 512 + tid] = m0 / n;
  out[b * 512 + 256 + tid] = m1 / n;
}

// ---------------------------------------------------------------------------
// Host orchestration
// ---------------------------------------------------------------------------
extern "C" void kernel_launch(void* const* d_in, const int* in_sizes, int n_in,
                              void* d_out, int out_size, void* d_ws, size_t ws_size,
                              hipStream_t stream)
{
  const float* tokens  = (const float*)d_in[0];
  const float* centers = (const float*)d_in[1];
  // d_in[2] = lrfs: dead in the reference (gathered, never consumed)
  const float* wq      = (const float*)d_in[3];
  const float* wkv     = (const float*)d_in[4];
  const float* mlp_w1  = (const float*)d_in[5];
  const float* mlp_b1  = (const float*)d_in[6];
  const float* mlp_w2  = (const float*)d_in[7];
  const float* mlp_b2  = (const float*)d_in[8];
  const float* bn1_g   = (const float*)d_in[9];
  const float* bn1_b   = (const float*)d_in[10];
  const float* bn2_g   = (const float*)d_in[11];
  const float* bn2_b   = (const float*)d_in[12];
  const float* att_w1  = (const float*)d_in[13];
  const float* att_b1  = (const float*)d_in[14];
  const float* att_w2  = (const float*)d_in[15];
  const float* att_b2  = (const float*)d_in[16];
  const float* emb_w   = (const float*)d_in[17];
  const float* emb_b   = (const float*)d_in[18];
  const float* embn_g  = (const float*)d_in[19];
  const float* embn_b  = (const float*)d_in[20];
  (void)in_sizes; (void)n_in; (void)out_size; (void)ws_size;

  char* ws = (char*)d_ws;
  size_t off = 0;
  auto alloc = [&](size_t bytes) -> void* {
    void* p = ws + off;
    off += (bytes + 255) & ~(size_t)255;
    return p;
  };
  const size_t tokMax  = (size_t)BB * 512 * CC * 4;   // 8 MB
  const size_t tgtMax  = (size_t)BB * 1024 * CC * 4;  // 16 MB
  float* tokA     = (float*)alloc(tokMax);
  float* tokB     = (float*)alloc(tokMax);
  float* ctrA     = (float*)alloc((size_t)BB * 512 * 3 * 4);
  float* ctrB     = (float*)alloc((size_t)BB * 512 * 3 * 4);
  float* tokq_raw = (float*)alloc(tokMax);
  float* tokq_bn  = (float*)alloc(tokMax);
  float* tokt_bn  = (float*)alloc(tgtMax);
  float* Qw1      = (float*)alloc(tokMax);
  float* Kw1      = (float*)alloc(tgtMax);
  float* Vbuf     = (float*)alloc(tgtMax);
  float* tq1      = (float*)alloc(tokMax);
  float* tqbn     = (float*)alloc(tokMax);
  float* mlph     = (float*)alloc((size_t)BB * 512 * 512 * 4);
  float* WFq      = (float*)alloc((size_t)3 * CC * CC * 4);
  float* WFk      = (float*)alloc((size_t)3 * CC * CC * 4);
  int*   rep      = (int*)alloc((size_t)BB * 512 * 4);
  int*   nnb      = (int*)alloc((size_t)BB * 512 * 64 * 4);
  float* bnpart   = (float*)alloc((size_t)64 * 512 * 4);
  float* bnmean   = (float*)alloc(256 * 4);
  float* bnrstd   = (float*)alloc(256 * 4);
  float* gmeanb   = (float*)alloc((size_t)BB * CC * 4);
  float* gembb    = (float*)alloc((size_t)BB * EE * 4);
  float* grelub   = (float*)alloc((size_t)BB * EE * 4);

  const int NC[3] = {512, 256, 128};
  const int NN[3] = {16, 32, 64};

  // Weight folds: WFq_i = wq_i @ att_w1_i ; WFk_i = wkv_i[:, :C] @ att_w1_i
  for (int i = 0; i < 3; ++i) {
    gemm_kernel<<<dim3(4, 4), 256, 0, stream>>>(
        wq + (size_t)i * CC * CC, CC, att_w1 + (size_t)i * CC * CC, CC,
        nullptr, nullptr, WFq + (size_t)i * CC * CC, CC, CC, CC, 0);
    gemm_kernel<<<dim3(4, 4), 256, 0, stream>>>(
        wkv + (size_t)i * CC * 512, 512, att_w1 + (size_t)i * CC * CC, CC,
        nullptr, nullptr, WFk + (size_t)i * CC * CC, CC, CC, CC, 0);
  }

  const float* cur_tok = tokens;
  const float* cur_ctr = centers;
  int curTt = TT0;

  float* tok_bufs[2] = {tokA, tokB};
  float* ctr_bufs[2] = {ctrA, ctrB};

  for (int i = 0; i < 3; ++i) {
    int Tq = NC[i], Kn = NN[i], Tt = curTt;
    float* ctr_q = ctr_bufs[i & 1];
    float* tok_next = tok_bufs[i & 1];
    int M = BB * Tq;
    int Mt = BB * Tt;

    // FPS + gathers + kNN (index-exact)
    fps_kernel<<<BB, Tt, 0, stream>>>(cur_ctr, Tt, Tq, rep);
    {
      int tot = BB * Tq * 3;
      gather_rows_kernel<<<(tot + 255) / 256, 256, 0, stream>>>(
          cur_ctr, rep, ctr_q, Tq, Tt, 3, tot);
    }
    {
      int tot = M * CC;
      gather_rows_kernel<<<(tot + 255) / 256, 256, 0, stream>>>(
          cur_tok, rep, tokq_raw, Tq, Tt, CC, tot);
    }
    knn_kernel<<<M, 256, 0, stream>>>(ctr_q, cur_ctr, Tq, Tt, Kn, nnb);

    // Optional BN1 over concat(query, target)
    const float* q_src;
    const float* t_src;
    if (i == 0) {
      q_src = tokq_raw;
      t_src = cur_tok;
    } else {
      int R1 = M, R2 = Mt;
      bn_stats_kernel<<<64, 256, 0, stream>>>(tokq_raw, R1, cur_tok, R2, bnpart, 64);
      bn_finalize_kernel<<<1, 256, 0, stream>>>(bnpart, 64, R1 + R2, bnmean, bnrstd);
      {
        int tot = R1 * CC;
        bn_apply_kernel<<<(tot + 255) / 256, 256, 0, stream>>>(
            tokq_raw, tokq_bn, bnmean, bnrstd, bn1_g + i * CC, bn1_b + i * CC, tot);
      }
      {
        int tot = R2 * CC;
        bn_apply_kernel<<<(tot + 255) / 256, 256, 0, stream>>>(
            cur_tok, tokt_bn, bnmean, bnrstd, bn1_g + i * CC, bn1_b + i * CC, tot);
      }
      q_src = tokq_bn;
      t_src = tokt_bn;
    }

    // Projections (folded): Qw1 = q @ (wq@w1); Kw1 = t @ (wkv_K@w1); V = t @ wkv_V
    gemm_kernel<<<dim3(CC / 64, M / 64), 256, 0, stream>>>(
        q_src, CC, WFq + (size_t)i * CC * CC, CC, nullptr, nullptr,
        Qw1, M, CC, CC, 0);
    gemm_kernel<<<dim3(CC / 64, Mt / 64), 256, 0, stream>>>(
        t_src, CC, WFk + (size_t)i * CC * CC, CC, nullptr, nullptr,
        Kw1, Mt, CC, CC, 0);
    gemm_kernel<<<dim3(CC / 64, Mt / 64), 256, 0, stream>>>(
        t_src, CC, wkv + (size_t)i * CC * 512 + CC, 512, nullptr, nullptr,
        Vbuf, Mt, CC, CC, 0);

    // Fused neighborhood attention (+ skip)
    if (Kn == 16)
      attn2_kernel<16><<<dim3(Tq, BB), 256, 0, stream>>>(
          Qw1, Kw1, Vbuf, nnb, att_b1 + i * CC,
          att_w2 + (size_t)i * CC * CC, att_b2 + i * CC, tokq_raw, tq1, Tq, Tt);
    else if (Kn == 32)
      attn2_kernel<32><<<dim3(Tq, BB), 256, 0, stream>>>(
          Qw1, Kw1, Vbuf, nnb, att_b1 + i * CC,
          att_w2 + (size_t)i * CC * CC, att_b2 + i * CC, tokq_raw, tq1, Tq, Tt);
    else
      attn2_kernel<64><<<dim3(Tq, BB), 256, 0, stream>>>(
          Qw1, Kw1, Vbuf, nnb, att_b1 + i * CC,
          att_w2 + (size_t)i * CC * CC, att_b2 + i * CC, tokq_raw, tq1, Tq, Tt);

    // BN2 + MLP (+ skip2)
    bn_stats_kernel<<<64, 256, 0, stream>>>(tq1, M, tq1, 0, bnpart, 64);
    bn_finalize_kernel<<<1, 256, 0, stream>>>(bnpart, 64, M, bnmean, bnrstd);
    {
      int tot = M * CC;
      bn_apply_kernel<<<(tot + 255) / 256, 256, 0, stream>>>(
          tq1, tqbn, bnmean, bnrstd, bn2_g + i * CC, bn2_b + i * CC, tot);
    }
    gemm_kernel<<<dim3(512 / 64, M / 64), 256, 0, stream>>>(
        tqbn, CC, mlp_w1 + (size_t)i * CC * 512, 512, mlp_b1 + i * 512, nullptr,
        mlph, M, 512, CC, 1);
    gemm_kernel<<<dim3(CC / 64, M / 64), 256, 0, stream>>>(
        mlph, 512, mlp_w2 + (size_t)i * 512 * CC, CC, mlp_b2 + i * CC, tq1,
        tok_next, M, CC, 512, 0);

    cur_tok = tok_next;
    cur_ctr = ctr_q;
    curTt = Tq;
  }

  // Final head: mean -> emb GEMM -> BN+relu -> top64 threshold -> L2 normalize
  gmean_kernel<<<(BB * CC + 255) / 256, 256, 0, stream>>>(cur_tok, gmeanb, curTt);
  gemm_kernel<<<dim3(EE / 64, 1), 256, 0, stream>>>(
      gmeanb, CC, emb_w, EE, emb_b, nullptr, gembb, BB, EE, CC, 0);
  embbn_kernel<<<2, 256, 0, stream>>>(gembb, embn_g, embn_b, grelub);
  topk_norm_kernel<<<BB, 256, 0, stream>>>(grelub, (float*)d_out);
}

// Round 3
// 2489.314 us; speedup vs baseline: 1.6488x; 1.2613x over previous
//
#include <hip/hip_runtime.h>
#include <cstdint>
#include <cmath>

// Problem constants
static constexpr int BB = 16;    // batch
static constexpr int TT0 = 1024; // initial tokens
static constexpr int CC = 256;   // channels
static constexpr int EE = 512;   // embedding

// ---------------------------------------------------------------------------
// FPS, single-wave version: one 64-lane wave per batch, NPL = Tt/64 points
// per lane in registers. No barriers; argmax via 6-step shfl_xor butterfly on
// a packed u64 key (float bits of d << 32 | ~idx) -- exact jnp.argmax
// first-index tie semantics since d >= 0 (monotone bit pattern).
// Distance math identical (fp32 _rn ops, ((dx*dx+dy*dy)+dz*dz)).
// Center lookup: one ds_read_b128 at wave-uniform address (broadcast).
// ---------------------------------------------------------------------------
template <int NPL>
__global__ __launch_bounds__(64) void fps_wave_kernel(
    const float* __restrict__ ctr, int Tt, int Ksel, int* __restrict__ rep)
{
  __shared__ float4 sp[1024];
  int b = blockIdx.x;
  int lane = threadIdx.x;
  const float* base = ctr + (size_t)b * Tt * 3;
  float x[NPL], y[NPL], z[NPL], d[NPL];
  #pragma unroll
  for (int j = 0; j < NPL; ++j) {
    int idx = lane * NPL + j;
    x[j] = base[idx * 3 + 0];
    y[j] = base[idx * 3 + 1];
    z[j] = base[idx * 3 + 2];
    d[j] = INFINITY;
    sp[idx] = make_float4(x[j], y[j], z[j], 0.f);
  }
  // single wave: LDS writes by this wave are visible after lgkmcnt drain
  // (compiler inserts waits before dependent ds_read).
  int cur = 0;
  for (int s = 0; s < Ksel; ++s) {
    if (lane == 0) rep[b * Ksel + s] = cur;
    float4 cpt = sp[cur];  // uniform address -> broadcast
    unsigned long long key = 0ull;
    #pragma unroll
    for (int j = 0; j < NPL; ++j) {
      float dx = __fsub_rn(x[j], cpt.x);
      float dy = __fsub_rn(y[j], cpt.y);
      float dz = __fsub_rn(z[j], cpt.z);
      float dist = __fadd_rn(__fadd_rn(__fmul_rn(dx, dx), __fmul_rn(dy, dy)),
                             __fmul_rn(dz, dz));
      float nd = fminf(d[j], dist);
      d[j] = nd;
      unsigned long long kj =
          ((unsigned long long)__float_as_uint(nd) << 32) |
          (unsigned)(0xFFFFFFFFu - (unsigned)(lane * NPL + j));
      key = (kj > key) ? kj : key;
    }
    #pragma unroll
    for (int off = 32; off > 0; off >>= 1) {
      unsigned long long ok = __shfl_xor(key, off);
      key = (ok > key) ? ok : key;
    }
    cur = (int)(0xFFFFFFFFu - (unsigned)(key & 0xFFFFFFFFull));
  }
}

// ---------------------------------------------------------------------------
// kNN: one block (256 thr) per query row. Exact fp32 ops in reference order;
// k iterative argmin with first-index ties (== lax.top_k(-d2,k) order).
// ---------------------------------------------------------------------------
__global__ __launch_bounds__(256) void knn_kernel(
    const float* __restrict__ cq, const float* __restrict__ ct,
    int Tq, int Tt, int Kn, int* __restrict__ nn)
{
  int r = blockIdx.x;     // b*Tq + q
  int b = r / Tq;
  __shared__ float d2[1024];
  __shared__ float wv[4];
  __shared__ int wi[4];
  int tid = threadIdx.x, lane = tid & 63, wid = tid >> 6;
  float qx = cq[(size_t)r * 3 + 0];
  float qy = cq[(size_t)r * 3 + 1];
  float qz = cq[(size_t)r * 3 + 2];
  float sq = __fadd_rn(__fadd_rn(__fmul_rn(qx, qx), __fmul_rn(qy, qy)),
                       __fmul_rn(qz, qz));
  for (int t = tid; t < Tt; t += 256) {
    const float* tp = ct + ((size_t)b * Tt + t) * 3;
    float tx = tp[0], ty = tp[1], tz = tp[2];
    float st = __fadd_rn(__fadd_rn(__fmul_rn(tx, tx), __fmul_rn(ty, ty)),
                         __fmul_rn(tz, tz));
    float dot = __fadd_rn(__fadd_rn(__fmul_rn(qx, tx), __fmul_rn(qy, ty)),
                          __fmul_rn(qz, tz));
    d2[t] = __fsub_rn(__fadd_rn(sq, st), __fmul_rn(2.0f, dot));
  }
  __syncthreads();
  for (int j = 0; j < Kn; ++j) {
    float v = INFINITY; int ix = 0x7fffffff;
    for (int t = tid; t < Tt; t += 256) {
      float dv = d2[t];
      if (dv < v) { v = dv; ix = t; }
    }
    #pragma unroll
    for (int off = 32; off > 0; off >>= 1) {
      float ov = __shfl_down(v, off);
      int oi = __shfl_down(ix, off);
      if (ov < v || (ov == v && oi < ix)) { v = ov; ix = oi; }
    }
    if (lane == 0) { wv[wid] = v; wi[wid] = ix; }
    __syncthreads();
    if (tid == 0) {
      float bv = wv[0]; int bi = wi[0];
      for (int w = 1; w < 4; ++w)
        if (wv[w] < bv || (wv[w] == bv && wi[w] < bi)) { bv = wv[w]; bi = wi[w]; }
      nn[(size_t)r * Kn + j] = bi;
      d2[bi] = INFINITY;
    }
    __syncthreads();
  }
}

// ---------------------------------------------------------------------------
// Row gather: dst[b,q,:] = src[b, idx[b,q], :]
// ---------------------------------------------------------------------------
__global__ void gather_rows_kernel(
    const float* __restrict__ src, const int* __restrict__ idx,
    float* __restrict__ dst, int Tq, int Tt, int D, int total)
{
  int i = blockIdx.x * blockDim.x + threadIdx.x;
  if (i >= total) return;
  int d = i % D;
  int q = (i / D) % Tq;
  int b = i / (D * Tq);
  int s = idx[b * Tq + q];
  dst[i] = src[((size_t)b * Tt + s) * D + d];
}

// ---------------------------------------------------------------------------
// BatchNorm over rows (axis 0), C = 256 channels.
// ---------------------------------------------------------------------------
__global__ __launch_bounds__(256) void bn_stats_kernel(
    const float* __restrict__ x1, int R1, const float* __restrict__ x2, int R2,
    float* __restrict__ part, int nch)
{
  int c = threadIdx.x;
  int chunk = blockIdx.x;
  int R = R1 + R2;
  int per = (R + nch - 1) / nch;
  int r0 = chunk * per;
  int r1 = min(r0 + per, R);
  float s = 0.f, ss = 0.f;
  for (int r = r0; r < r1; ++r) {
    float v = (r < R1) ? x1[(size_t)r * 256 + c] : x2[(size_t)(r - R1) * 256 + c];
    s += v;
    ss = fmaf(v, v, ss);
  }
  part[(size_t)chunk * 512 + c] = s;
  part[(size_t)chunk * 512 + 256 + c] = ss;
}

__global__ __launch_bounds__(256) void bn_finalize_kernel(
    const float* __restrict__ part, int nch, int R,
    float* __restrict__ mean, float* __restrict__ rstd)
{
  int c = threadIdx.x;
  float s = 0.f, ss = 0.f;
  for (int k = 0; k < nch; ++k) {
    s += part[(size_t)k * 512 + c];
    ss += part[(size_t)k * 512 + 256 + c];
  }
  float m = s / (float)R;
  float v = ss / (float)R - m * m;
  if (v < 0.f) v = 0.f;
  mean[c] = m;
  rstd[c] = rsqrtf(v + 1e-5f);
}

__global__ void bn_apply_kernel(
    const float* __restrict__ x, float* __restrict__ y,
    const float* __restrict__ mean, const float* __restrict__ rstd,
    const float* __restrict__ g, const float* __restrict__ bta, int total)
{
  int i = blockIdx.x * blockDim.x + threadIdx.x;
  if (i >= total) return;
  int c = i & 255;
  y[i] = (x[i] - mean[c]) * rstd[c] * g[c] + bta[c];
}

// ---------------------------------------------------------------------------
// fp32 tiled GEMM: out = A(MxK, row stride lda) @ W(KxN, row stride ldw)
//                  [+bias] [relu] [+resid]
// BM=BN=64, BK=32, 256 threads, 4x4 per thread, float4 global loads.
// ---------------------------------------------------------------------------
__global__ __launch_bounds__(256) void gemm_kernel(
    const float* __restrict__ A, int lda,
    const float* __restrict__ W, int ldw,
    const float* __restrict__ bias, const float* __restrict__ resid,
    float* __restrict__ out, int M, int N, int K, int relu)
{
  __shared__ float As[32][68];
  __shared__ float Bs[32][68];
  int bm = blockIdx.y * 64;
  int bn = blockIdx.x * 64;
  int tid = threadIdx.x;
  int tx = tid & 15, ty = tid >> 4;
  int arow = tid >> 3;          // 0..31
  int ak = (tid & 7) * 4;       // 0,4,...,28
  int wk = tid >> 4;            // 0..15
  int wn = (tid & 15) * 4;      // 0..60
  float acc[4][4] = {{0.f}};
  for (int k0 = 0; k0 < K; k0 += 32) {
    #pragma unroll
    for (int h = 0; h < 2; ++h) {
      int row = bm + arow + h * 32;
      float4 a = (row < M)
          ? *(const float4*)&A[(size_t)row * lda + k0 + ak]
          : make_float4(0.f, 0.f, 0.f, 0.f);
      As[ak + 0][arow + h * 32] = a.x;
      As[ak + 1][arow + h * 32] = a.y;
      As[ak + 2][arow + h * 32] = a.z;
      As[ak + 3][arow + h * 32] = a.w;
    }
    #pragma unroll
    for (int h = 0; h < 2; ++h) {
      int krow = k0 + wk + h * 16;
      *(float4*)&Bs[wk + h * 16][wn] =
          *(const float4*)&W[(size_t)krow * ldw + bn + wn];
    }
    __syncthreads();
    #pragma unroll
    for (int k = 0; k < 32; ++k) {
      float4 a = *(const float4*)&As[k][ty * 4];
      float4 b = *(const float4*)&Bs[k][tx * 4];
      float av[4] = {a.x, a.y, a.z, a.w};
      float bv[4] = {b.x, b.y, b.z, b.w};
      #pragma unroll
      for (int i = 0; i < 4; ++i)
        #pragma unroll
        for (int j = 0; j < 4; ++j)
          acc[i][j] = fmaf(av[i], bv[j], acc[i][j]);
    }
    __syncthreads();
  }
  #pragma unroll
  for (int i = 0; i < 4; ++i) {
    int m = bm + ty * 4 + i;
    if (m >= M) continue;
    #pragma unroll
    for (int j = 0; j < 4; ++j) {
      int n = bn + tx * 4 + j;
      float v = acc[i][j];
      if (bias) v += bias[n];
      if (relu) v = fmaxf(v, 0.f);
      if (resid) v += resid[(size_t)m * N + n];
      out[(size_t)m * N + n] = v;
    }
  }
}

// ---------------------------------------------------------------------------
// Fused per-query-row attention (folded w1):
//   h_j[c] = relu(Qw[r][c] - Kw[nn_j][c] + b1[c])
//   sim_j  = h_j @ w2 + b2      (h staged in LDS, XOR-swizzled)
//   A      = softmax over j (online across j-groups of <=32)
//   out    = sum_j A*V[nn_j] + skip
// ---------------------------------------------------------------------------
template <int KN>
__global__ __launch_bounds__(256) void attn2_kernel(
    const float* __restrict__ Qw, const float* __restrict__ Kw,
    const float* __restrict__ Vb, const int* __restrict__ nn,
    const float* __restrict__ b1, const float* __restrict__ w2,
    const float* __restrict__ b2, const float* __restrict__ skip,
    float* __restrict__ out, int Tq, int Tt)
{
  constexpr int JG = (KN < 32) ? KN : 32;   // j-group size
  constexpr int NG = KN / JG;
  constexpr int J4 = JG / 4;
  constexpr int MASK = J4 - 1;
  __shared__ float4 h4[256 * J4];
  __shared__ int nns[KN];
  int q = blockIdx.x, b = blockIdx.y;
  int r = b * Tq + q;
  int c = threadIdx.x;
  if (c < KN) nns[c] = nn[(size_t)r * KN + c];
  __syncthreads();
  float qw = Qw[(size_t)r * 256 + c];
  float bb1 = b1[c];
  float bb2 = b2[c];
  const float* kwb = Kw + (size_t)b * Tt * 256;
  const float* vbb = Vb + (size_t)b * Tt * 256;
  float m = -INFINITY, ssum = 0.f, o = 0.f;
  #pragma unroll
  for (int g = 0; g < NG; ++g) {
    if (g) __syncthreads();   // prior group's LDS reads must finish
    #pragma unroll
    for (int j4 = 0; j4 < J4; ++j4) {
      float4 t;
      t.x = fmaxf(qw - kwb[(size_t)nns[g * JG + j4 * 4 + 0] * 256 + c] + bb1, 0.f);
      t.y = fmaxf(qw - kwb[(size_t)nns[g * JG + j4 * 4 + 1] * 256 + c] + bb1, 0.f);
      t.z = fmaxf(qw - kwb[(size_t)nns[g * JG + j4 * 4 + 2] * 256 + c] + bb1, 0.f);
      t.w = fmaxf(qw - kwb[(size_t)nns[g * JG + j4 * 4 + 3] * 256 + c] + bb1, 0.f);
      h4[c * J4 + (j4 ^ (c & MASK))] = t;
    }
    __syncthreads();
    float acc[JG];
    #pragma unroll
    for (int j = 0; j < JG; ++j) acc[j] = bb2;
    const float* wp = w2 + c;
    #pragma unroll 4
    for (int d = 0; d < 256; ++d) {
      float w = wp[d * 256];
      int base = d * J4;
      int key = d & MASK;
      #pragma unroll
      for (int j4 = 0; j4 < J4; ++j4) {
        float4 v = h4[base + (j4 ^ key)];
        acc[j4 * 4 + 0] = fmaf(v.x, w, acc[j4 * 4 + 0]);
        acc[j4 * 4 + 1] = fmaf(v.y, w, acc[j4 * 4 + 1]);
        acc[j4 * 4 + 2] = fmaf(v.z, w, acc[j4 * 4 + 2]);
        acc[j4 * 4 + 3] = fmaf(v.w, w, acc[j4 * 4 + 3]);
      }
    }
    // online softmax update across groups
    float gm = acc[0];
    #pragma unroll
    for (int j = 1; j < JG; ++j) gm = fmaxf(gm, acc[j]);
    if (gm > m) {
      float sc = expf(m - gm);   // m==-inf on first group -> 0
      ssum *= sc;
      o *= sc;
      m = gm;
    }
    #pragma unroll
    for (int j = 0; j < JG; ++j) {
      float e = expf(acc[j] - m);
      ssum += e;
      float vv = vbb[(size_t)nns[g * JG + j] * 256 + c];
      o = fmaf(e, vv, o);
    }
  }
  out[(size_t)r * 256 + c] = o / ssum + skip[(size_t)r * 256 + c];
}

// ---------------------------------------------------------------------------
// Final head
// ---------------------------------------------------------------------------
__global__ void gmean_kernel(const float* __restrict__ tok,
                             float* __restrict__ out, int Tt)
{
  int i = blockIdx.x * blockDim.x + threadIdx.x;
  if (i >= BB * CC) return;
  int b = i >> 8;
  int c = i & 255;
  float s = 0.f;
  for (int t = 0; t < Tt; ++t) s += tok[((size_t)b * Tt + t) * 256 + c];
  out[i] = s / (float)Tt;
}

__global__ void embbn_kernel(const float* __restrict__ x,
                             const float* __restrict__ g,
                             const float* __restrict__ bta,
                             float* __restrict__ y)
{
  int e = blockIdx.x * blockDim.x + threadIdx.x;
  if (e >= EE) return;
  float s = 0.f;
  for (int r = 0; r < BB; ++r) s += x[r * EE + e];
  float m = s / (float)BB;
  float vs = 0.f;
  for (int r = 0; r < BB; ++r) {
    float d = x[r * EE + e] - m;
    vs = fmaf(d, d, vs);
  }
  float rs = rsqrtf(vs / (float)BB + 1e-5f);
  for (int r = 0; r < BB; ++r) {
    float val = (x[r * EE + e] - m) * rs * g[e] + bta[e];
    y[r * EE + e] = fmaxf(val, 0.f);
  }
}

__global__ __launch_bounds__(256) void topk_norm_kernel(
    const float* __restrict__ gin, float* __restrict__ out)
{
  int b = blockIdx.x, tid = threadIdx.x, lane = tid & 63, wid = tid >> 6;
  __shared__ float vals[512];
  __shared__ float wv[4];
  __shared__ int wi[4];
  __shared__ float sh;
  float g0 = gin[b * 512 + tid];
  float g1 = gin[b * 512 + 256 + tid];
  vals[tid] = g0;
  vals[256 + tid] = g1;
  __syncthreads();
  for (int it = 0; it < 64; ++it) {
    float v = vals[tid];
    int ix = tid;
    float u = vals[256 + tid];
    if (u > v) { v = u; ix = 256 + tid; }
    #pragma unroll
    for (int off = 32; off > 0; off >>= 1) {
      float ov = __shfl_down(v, off);
      int oi = __shfl_down(ix, off);
      if (ov > v || (ov == v && oi < ix)) { v = ov; ix = oi; }
    }
    if (lane == 0) { wv[wid] = v; wi[wid] = ix; }
    __syncthreads();
    if (tid == 0) {
      float bv = wv[0]; int bi = wi[0];
      for (int w = 1; w < 4; ++w)
        if (wv[w] > bv || (wv[w] == bv && wi[w] < bi)) { bv = wv[w]; bi = wi[w]; }
      vals[bi] = -INFINITY;
      sh = bv;
    }
    __syncthreads();
  }
  float thr = sh;
  float m0 = (g0 >= thr) ? g0 : 0.f;
  float m1 = (g1 >= thr) ? g1 : 0.f;
  float ss = m0 * m0 + m1 * m1;
  #pragma unroll
  for (int off = 32; off > 0; off >>= 1) ss += __shfl_down(ss, off);
  if (lane == 0) wv[wid] = ss;
  __syncthreads();
  if (tid == 0) {
    float t = wv[0] + wv[1] + wv[2] + wv[3];
    sh = fmaxf(sqrtf(t), 1e-12f);
  }
  __syncthreads();
  float n = sh;
  out[b * 512 + tid] = m0 / n;
  out[b * 512 + 256 + tid] = m1 / n;
}

// ---------------------------------------------------------------------------
// Host orchestration
// ---------------------------------------------------------------------------
extern "C" void kernel_launch(void* const* d_in, const int* in_sizes, int n_in,
                              void* d_out, int out_size, void* d_ws, size_t ws_size,
                              hipStream_t stream)
{
  const float* tokens  = (const float*)d_in[0];
  const float* centers = (const float*)d_in[1];
  // d_in[2] = lrfs: dead in the reference (gathered, never consumed)
  const float* wq      = (const float*)d_in[3];
  const float* wkv     = (const float*)d_in[4];
  const float* mlp_w1  = (const float*)d_in[5];
  const float* mlp_b1  = (const float*)d_in[6];
  const float* mlp_w2  = (const float*)d_in[7];
  const float* mlp_b2  = (const float*)d_in[8];
  const float* bn1_g   = (const float*)d_in[9];
  const float* bn1_b   = (const float*)d_in[10];
  const float* bn2_g   = (const float*)d_in[11];
  const float* bn2_b   = (const float*)d_in[12];
  const float* att_w1  = (const float*)d_in[13];
  const float* att_b1  = (const float*)d_in[14];
  const float* att_w2  = (const float*)d_in[15];
  const float* att_b2  = (const float*)d_in[16];
  const float* emb_w   = (const float*)d_in[17];
  const float* emb_b   = (const float*)d_in[18];
  const float* embn_g  = (const float*)d_in[19];
  const float* embn_b  = (const float*)d_in[20];
  (void)in_sizes; (void)n_in; (void)out_size; (void)ws_size;

  char* ws = (char*)d_ws;
  size_t off = 0;
  auto alloc = [&](size_t bytes) -> void* {
    void* p = ws + off;
    off += (bytes + 255) & ~(size_t)255;
    return p;
  };
  const size_t tokMax  = (size_t)BB * 512 * CC * 4;   // 8 MB
  const size_t tgtMax  = (size_t)BB * 1024 * CC * 4;  // 16 MB
  float* tokA     = (float*)alloc(tokMax);
  float* tokB     = (float*)alloc(tokMax);
  float* ctrA     = (float*)alloc((size_t)BB * 512 * 3 * 4);
  float* ctrB     = (float*)alloc((size_t)BB * 512 * 3 * 4);
  float* tokq_raw = (float*)alloc(tokMax);
  float* tokq_bn  = (float*)alloc(tokMax);
  float* tokt_bn  = (float*)alloc(tgtMax);
  float* Qw1      = (float*)alloc(tokMax);
  float* Kw1      = (float*)alloc(tgtMax);
  float* Vbuf     = (float*)alloc(tgtMax);
  float* tq1      = (float*)alloc(tokMax);
  float* tqbn     = (float*)alloc(tokMax);
  float* mlph     = (float*)alloc((size_t)BB * 512 * 512 * 4);
  float* WFq      = (float*)alloc((size_t)3 * CC * CC * 4);
  float* WFk      = (float*)alloc((size_t)3 * CC * CC * 4);
  int*   rep      = (int*)alloc((size_t)BB * 512 * 4);
  int*   nnb      = (int*)alloc((size_t)BB * 512 * 64 * 4);
  float* bnpart   = (float*)alloc((size_t)64 * 512 * 4);
  float* bnmean   = (float*)alloc(256 * 4);
  float* bnrstd   = (float*)alloc(256 * 4);
  float* gmeanb   = (float*)alloc((size_t)BB * CC * 4);
  float* gembb    = (float*)alloc((size_t)BB * EE * 4);
  float* grelub   = (float*)alloc((size_t)BB * EE * 4);

  const int NC[3] = {512, 256, 128};
  const int NN[3] = {16, 32, 64};

  // Weight folds: WFq_i = wq_i @ att_w1_i ; WFk_i = wkv_i[:, :C] @ att_w1_i
  for (int i = 0; i < 3; ++i) {
    gemm_kernel<<<dim3(4, 4), 256, 0, stream>>>(
        wq + (size_t)i * CC * CC, CC, att_w1 + (size_t)i * CC * CC, CC,
        nullptr, nullptr, WFq + (size_t)i * CC * CC, CC, CC, CC, 0);
    gemm_kernel<<<dim3(4, 4), 256, 0, stream>>>(
        wkv + (size_t)i * CC * 512, 512, att_w1 + (size_t)i * CC * CC, CC,
        nullptr, nullptr, WFk + (size_t)i * CC * CC, CC, CC, CC, 0);
  }

  const float* cur_tok = tokens;
  const float* cur_ctr = centers;
  int curTt = TT0;

  float* tok_bufs[2] = {tokA, tokB};
  float* ctr_bufs[2] = {ctrA, ctrB};

  for (int i = 0; i < 3; ++i) {
    int Tq = NC[i], Kn = NN[i], Tt = curTt;
    float* ctr_q = ctr_bufs[i & 1];
    float* tok_next = tok_bufs[i & 1];
    int M = BB * Tq;
    int Mt = BB * Tt;

    // FPS (single-wave) + gathers + kNN (index-exact)
    if (Tt == 1024)
      fps_wave_kernel<16><<<BB, 64, 0, stream>>>(cur_ctr, Tt, Tq, rep);
    else if (Tt == 512)
      fps_wave_kernel<8><<<BB, 64, 0, stream>>>(cur_ctr, Tt, Tq, rep);
    else
      fps_wave_kernel<4><<<BB, 64, 0, stream>>>(cur_ctr, Tt, Tq, rep);
    {
      int tot = BB * Tq * 3;
      gather_rows_kernel<<<(tot + 255) / 256, 256, 0, stream>>>(
          cur_ctr, rep, ctr_q, Tq, Tt, 3, tot);
    }
    {
      int tot = M * CC;
      gather_rows_kernel<<<(tot + 255) / 256, 256, 0, stream>>>(
          cur_tok, rep, tokq_raw, Tq, Tt, CC, tot);
    }
    knn_kernel<<<M, 256, 0, stream>>>(ctr_q, cur_ctr, Tq, Tt, Kn, nnb);

    // Optional BN1 over concat(query, target)
    const float* q_src;
    const float* t_src;
    if (i == 0) {
      q_src = tokq_raw;
      t_src = cur_tok;
    } else {
      int R1 = M, R2 = Mt;
      bn_stats_kernel<<<64, 256, 0, stream>>>(tokq_raw, R1, cur_tok, R2, bnpart, 64);
      bn_finalize_kernel<<<1, 256, 0, stream>>>(bnpart, 64, R1 + R2, bnmean, bnrstd);
      {
        int tot = R1 * CC;
        bn_apply_kernel<<<(tot + 255) / 256, 256, 0, stream>>>(
            tokq_raw, tokq_bn, bnmean, bnrstd, bn1_g + i * CC, bn1_b + i * CC, tot);
      }
      {
        int tot = R2 * CC;
        bn_apply_kernel<<<(tot + 255) / 256, 256, 0, stream>>>(
            cur_tok, tokt_bn, bnmean, bnrstd, bn1_g + i * CC, bn1_b + i * CC, tot);
      }
      q_src = tokq_bn;
      t_src = tokt_bn;
    }

    // Projections (folded): Qw1 = q @ (wq@w1); Kw1 = t @ (wkv_K@w1); V = t @ wkv_V
    gemm_kernel<<<dim3(CC / 64, M / 64), 256, 0, stream>>>(
        q_src, CC, WFq + (size_t)i * CC * CC, CC, nullptr, nullptr,
        Qw1, M, CC, CC, 0);
    gemm_kernel<<<dim3(CC / 64, Mt / 64), 256, 0, stream>>>(
        t_src, CC, WFk + (size_t)i * CC * CC, CC, nullptr, nullptr,
        Kw1, Mt, CC, CC, 0);
    gemm_kernel<<<dim3(CC / 64, Mt / 64), 256, 0, stream>>>(
        t_src, CC, wkv + (size_t)i * CC * 512 + CC, 512, nullptr, nullptr,
        Vbuf, Mt, CC, CC, 0);

    // Fused neighborhood attention (+ skip)
    if (Kn == 16)
      attn2_kernel<16><<<dim3(Tq, BB), 256, 0, stream>>>(
          Qw1, Kw1, Vbuf, nnb, att_b1 + i * CC,
          att_w2 + (size_t)i * CC * CC, att_b2 + i * CC, tokq_raw, tq1, Tq, Tt);
    else if (Kn == 32)
      attn2_kernel<32><<<dim3(Tq, BB), 256, 0, stream>>>(
          Qw1, Kw1, Vbuf, nnb, att_b1 + i * CC,
          att_w2 + (size_t)i * CC * CC, att_b2 + i * CC, tokq_raw, tq1, Tq, Tt);
    else
      attn2_kernel<64><<<dim3(Tq, BB), 256, 0, stream>>>(
          Qw1, Kw1, Vbuf, nnb, att_b1 + i * CC,
          att_w2 + (size_t)i * CC * CC, att_b2 + i * CC, tokq_raw, tq1, Tq, Tt);

    // BN2 + MLP (+ skip2)
    bn_stats_kernel<<<64, 256, 0, stream>>>(tq1, M, tq1, 0, bnpart, 64);
    bn_finalize_kernel<<<1, 256, 0, stream>>>(bnpart, 64, M, bnmean, bnrstd);
    {
      int tot = M * CC;
      bn_apply_kernel<<<(tot + 255) / 256, 256, 0, stream>>>(
          tq1, tqbn, bnmean, bnrstd, bn2_g + i * CC, bn2_b + i * CC, tot);
    }
    gemm_kernel<<<dim3(512 / 64, M / 64), 256, 0, stream>>>(
        tqbn, CC, mlp_w1 + (size_t)i * CC * 512, 512, mlp_b1 + i * 512, nullptr,
        mlph, M, 512, CC, 1);
    gemm_kernel<<<dim3(CC / 64, M / 64), 256, 0, stream>>>(
        mlph, 512, mlp_w2 + (size_t)i * 512 * CC, CC, mlp_b2 + i * CC, tq1,
        tok_next, M, CC, 512, 0);

    cur_tok = tok_next;
    cur_ctr = ctr_q;
    curTt = Tq;
  }

  // Final head: mean -> emb GEMM -> BN+relu -> top64 threshold -> L2 normalize
  gmean_kernel<<<(BB * CC + 255) / 256, 256, 0, stream>>>(cur_tok, gmeanb, curTt);
  gemm_kernel<<<dim3(EE / 64, 1), 256, 0, stream>>>(
      gmeanb, CC, emb_w, EE, emb_b, nullptr, gembb, BB, EE, CC, 0);
  embbn_kernel<<<2, 256, 0, stream>>>(gembb, embn_g, embn_b, grelub);
  topk_norm_kernel<<<BB, 256, 0, stream>>>(grelub, (float*)d_out);
}

// Round 5
// 2477.170 us; speedup vs baseline: 1.6569x; 1.0049x over previous
//
#include <hip/hip_runtime.h>
#include <cstdint>
#include <cmath>

// Problem constants
static constexpr int BB = 16;    // batch
static constexpr int TT0 = 1024; // initial tokens
static constexpr int CC = 256;   // channels
static constexpr int EE = 512;   // embedding

typedef __bf16 bf16x8 __attribute__((ext_vector_type(8)));
typedef float  f32x4  __attribute__((ext_vector_type(4)));

// ---------------------------------------------------------------------------
// FPS, single-wave version (verified round 2): one 64-lane wave per batch.
// ---------------------------------------------------------------------------
template <int NPL>
__global__ __launch_bounds__(64) void fps_wave_kernel(
    const float* __restrict__ ctr, int Tt, int Ksel, int* __restrict__ rep)
{
  __shared__ float4 sp[1024];
  int b = blockIdx.x;
  int lane = threadIdx.x;
  const float* base = ctr + (size_t)b * Tt * 3;
  float x[NPL], y[NPL], z[NPL], d[NPL];
  #pragma unroll
  for (int j = 0; j < NPL; ++j) {
    int idx = lane * NPL + j;
    x[j] = base[idx * 3 + 0];
    y[j] = base[idx * 3 + 1];
    z[j] = base[idx * 3 + 2];
    d[j] = INFINITY;
    sp[idx] = make_float4(x[j], y[j], z[j], 0.f);
  }
  int cur = 0;
  for (int s = 0; s < Ksel; ++s) {
    if (lane == 0) rep[b * Ksel + s] = cur;
    float4 cpt = sp[cur];  // uniform address -> broadcast
    unsigned long long key = 0ull;
    #pragma unroll
    for (int j = 0; j < NPL; ++j) {
      float dx = __fsub_rn(x[j], cpt.x);
      float dy = __fsub_rn(y[j], cpt.y);
      float dz = __fsub_rn(z[j], cpt.z);
      float dist = __fadd_rn(__fadd_rn(__fmul_rn(dx, dx), __fmul_rn(dy, dy)),
                             __fmul_rn(dz, dz));
      float nd = fminf(d[j], dist);
      d[j] = nd;
      unsigned long long kj =
          ((unsigned long long)__float_as_uint(nd) << 32) |
          (unsigned)(0xFFFFFFFFu - (unsigned)(lane * NPL + j));
      key = (kj > key) ? kj : key;
    }
    #pragma unroll
    for (int off = 32; off > 0; off >>= 1) {
      unsigned long long ok = __shfl_xor(key, off);
      key = (ok > key) ? ok : key;
    }
    cur = (int)(0xFFFFFFFFu - (unsigned)(key & 0xFFFFFFFFull));
  }
}

// ---------------------------------------------------------------------------
// kNN (index-exact, verified)
// ---------------------------------------------------------------------------
__global__ __launch_bounds__(256) void knn_kernel(
    const float* __restrict__ cq, const float* __restrict__ ct,
    int Tq, int Tt, int Kn, int* __restrict__ nn)
{
  int r = blockIdx.x;     // b*Tq + q
  int b = r / Tq;
  __shared__ float d2[1024];
  __shared__ float wv[4];
  __shared__ int wi[4];
  int tid = threadIdx.x, lane = tid & 63, wid = tid >> 6;
  float qx = cq[(size_t)r * 3 + 0];
  float qy = cq[(size_t)r * 3 + 1];
  float qz = cq[(size_t)r * 3 + 2];
  float sq = __fadd_rn(__fadd_rn(__fmul_rn(qx, qx), __fmul_rn(qy, qy)),
                       __fmul_rn(qz, qz));
  for (int t = tid; t < Tt; t += 256) {
    const float* tp = ct + ((size_t)b * Tt + t) * 3;
    float tx = tp[0], ty = tp[1], tz = tp[2];
    float st = __fadd_rn(__fadd_rn(__fmul_rn(tx, tx), __fmul_rn(ty, ty)),
                         __fmul_rn(tz, tz));
    float dot = __fadd_rn(__fadd_rn(__fmul_rn(qx, tx), __fmul_rn(qy, ty)),
                          __fmul_rn(qz, tz));
    d2[t] = __fsub_rn(__fadd_rn(sq, st), __fmul_rn(2.0f, dot));
  }
  __syncthreads();
  for (int j = 0; j < Kn; ++j) {
    float v = INFINITY; int ix = 0x7fffffff;
    for (int t = tid; t < Tt; t += 256) {
      float dv = d2[t];
      if (dv < v) { v = dv; ix = t; }
    }
    #pragma unroll
    for (int off = 32; off > 0; off >>= 1) {
      float ov = __shfl_down(v, off);
      int oi = __shfl_down(ix, off);
      if (ov < v || (ov == v && oi < ix)) { v = ov; ix = oi; }
    }
    if (lane == 0) { wv[wid] = v; wi[wid] = ix; }
    __syncthreads();
    if (tid == 0) {
      float bv = wv[0]; int bi = wi[0];
      for (int w = 1; w < 4; ++w)
        if (wv[w] < bv || (wv[w] == bv && wi[w] < bi)) { bv = wv[w]; bi = wi[w]; }
      nn[(size_t)r * Kn + j] = bi;
      d2[bi] = INFINITY;
    }
    __syncthreads();
  }
}

// ---------------------------------------------------------------------------
// Row gather
// ---------------------------------------------------------------------------
__global__ void gather_rows_kernel(
    const float* __restrict__ src, const int* __restrict__ idx,
    float* __restrict__ dst, int Tq, int Tt, int D, int total)
{
  int i = blockIdx.x * blockDim.x + threadIdx.x;
  if (i >= total) return;
  int d = i % D;
  int q = (i / D) % Tq;
  int b = i / (D * Tq);
  int s = idx[b * Tq + q];
  dst[i] = src[((size_t)b * Tt + s) * D + d];
}

// ---------------------------------------------------------------------------
// BatchNorm over rows (axis 0), C = 256 channels.
// ---------------------------------------------------------------------------
__global__ __launch_bounds__(256) void bn_stats_kernel(
    const float* __restrict__ x1, int R1, const float* __restrict__ x2, int R2,
    float* __restrict__ part, int nch)
{
  int c = threadIdx.x;
  int chunk = blockIdx.x;
  int R = R1 + R2;
  int per = (R + nch - 1) / nch;
  int r0 = chunk * per;
  int r1 = min(r0 + per, R);
  float s = 0.f, ss = 0.f;
  for (int r = r0; r < r1; ++r) {
    float v = (r < R1) ? x1[(size_t)r * 256 + c] : x2[(size_t)(r - R1) * 256 + c];
    s += v;
    ss = fmaf(v, v, ss);
  }
  part[(size_t)chunk * 512 + c] = s;
  part[(size_t)chunk * 512 + 256 + c] = ss;
}

__global__ __launch_bounds__(256) void bn_finalize_kernel(
    const float* __restrict__ part, int nch, int R,
    float* __restrict__ mean, float* __restrict__ rstd)
{
  int c = threadIdx.x;
  float s = 0.f, ss = 0.f;
  for (int k = 0; k < nch; ++k) {
    s += part[(size_t)k * 512 + c];
    ss += part[(size_t)k * 512 + 256 + c];
  }
  float m = s / (float)R;
  float v = ss / (float)R - m * m;
  if (v < 0.f) v = 0.f;
  mean[c] = m;
  rstd[c] = rsqrtf(v + 1e-5f);
}

__global__ void bn_apply_kernel(
    const float* __restrict__ x, float* __restrict__ y,
    const float* __restrict__ mean, const float* __restrict__ rstd,
    const float* __restrict__ g, const float* __restrict__ bta, int total)
{
  int i = blockIdx.x * blockDim.x + threadIdx.x;
  if (i >= total) return;
  int c = i & 255;
  y[i] = (x[i] - mean[c]) * rstd[c] * g[c] + bta[c];
}

// ---------------------------------------------------------------------------
// fp32 tiled GEMM (unchanged)
// ---------------------------------------------------------------------------
__global__ __launch_bounds__(256) void gemm_kernel(
    const float* __restrict__ A, int lda,
    const float* __restrict__ W, int ldw,
    const float* __restrict__ bias, const float* __restrict__ resid,
    float* __restrict__ out, int M, int N, int K, int relu)
{
  __shared__ float As[32][68];
  __shared__ float Bs[32][68];
  int bm = blockIdx.y * 64;
  int bn = blockIdx.x * 64;
  int tid = threadIdx.x;
  int tx = tid & 15, ty = tid >> 4;
  int arow = tid >> 3;          // 0..31
  int ak = (tid & 7) * 4;       // 0,4,...,28
  int wk = tid >> 4;            // 0..15
  int wn = (tid & 15) * 4;      // 0..60
  float acc[4][4] = {{0.f}};
  for (int k0 = 0; k0 < K; k0 += 32) {
    #pragma unroll
    for (int h = 0; h < 2; ++h) {
      int row = bm + arow + h * 32;
      float4 a = (row < M)
          ? *(const float4*)&A[(size_t)row * lda + k0 + ak]
          : make_float4(0.f, 0.f, 0.f, 0.f);
      As[ak + 0][arow + h * 32] = a.x;
      As[ak + 1][arow + h * 32] = a.y;
      As[ak + 2][arow + h * 32] = a.z;
      As[ak + 3][arow + h * 32] = a.w;
    }
    #pragma unroll
    for (int h = 0; h < 2; ++h) {
      int krow = k0 + wk + h * 16;
      *(float4*)&Bs[wk + h * 16][wn] =
          *(const float4*)&W[(size_t)krow * ldw + bn + wn];
    }
    __syncthreads();
    #pragma unroll
    for (int k = 0; k < 32; ++k) {
      float4 a = *(const float4*)&As[k][ty * 4];
      float4 b = *(const float4*)&Bs[k][tx * 4];
      float av[4] = {a.x, a.y, a.z, a.w};
      float bv[4] = {b.x, b.y, b.z, b.w};
      #pragma unroll
      for (int i = 0; i < 4; ++i)
        #pragma unroll
        for (int j = 0; j < 4; ++j)
          acc[i][j] = fmaf(av[i], bv[j], acc[i][j]);
    }
    __syncthreads();
  }
  #pragma unroll
  for (int i = 0; i < 4; ++i) {
    int m = bm + ty * 4 + i;
    if (m >= M) continue;
    #pragma unroll
    for (int j = 0; j < 4; ++j) {
      int n = bn + tx * 4 + j;
      float v = acc[i][j];
      if (bias) v += bias[n];
      if (relu) v = fmaxf(v, 0.f);
      if (resid) v += resid[(size_t)m * N + n];
      out[(size_t)m * N + n] = v;
    }
  }
}

// ---------------------------------------------------------------------------
// w2 transpose + bf16 hi/lo split: in w2[3][c][c'] f32 -> out [3][c'][c] bf16
// ---------------------------------------------------------------------------
__global__ __launch_bounds__(256) void split_w2_kernel(
    const float* __restrict__ w2, __bf16* __restrict__ hi,
    __bf16* __restrict__ lo)
{
  int i = blockIdx.x * 256 + threadIdx.x;   // over 3*65536
  int s = i >> 16;
  int e = i & 65535;
  int cp = e >> 8;   // c' (row of transposed)
  int cc = e & 255;  // c
  float v = w2[((size_t)s << 16) + cc * 256 + cp];
  __bf16 h = (__bf16)v;
  hi[i] = h;
  lo[i] = (__bf16)(v - (float)h);
}

// ---------------------------------------------------------------------------
// MFMA attention:
//   h[j][c] = relu(Qw[r][c] - Kw[nn_j][c] + b1[c]) built directly in A-frag
//   registers, hi/lo bf16 split; sim = h @ w2 via 3x mfma_f32_16x16x32_bf16
//   (split product), accumulated fp32; sim tiles -> LDS [KN][260];
//   epilogue (softmax over j + V gather + skip) identical to verified attn2.
// Wave w owns mtile mt = w/WPM and ntiles [nt0, nt0+NTW).
// ---------------------------------------------------------------------------
template <int KN>
__global__ __launch_bounds__(256) void attn3_kernel(
    const float* __restrict__ Qw, const float* __restrict__ Kw,
    const float* __restrict__ Vb, const int* __restrict__ nn,
    const float* __restrict__ b1, const __bf16* __restrict__ w2Thi,
    const __bf16* __restrict__ w2Tlo, const float* __restrict__ b2,
    const float* __restrict__ skip, float* __restrict__ out, int Tq, int Tt)
{
  constexpr int MT  = KN / 16;   // m-tiles (j dimension)
  constexpr int WPM = 4 / MT;    // waves per m-tile
  constexpr int NTW = 4 * MT;    // n-tiles per wave (16/WPM)
  constexpr int LD  = 260;       // sim row stride (2-way bank alias = free)
  __shared__ float sim[KN * LD];
  __shared__ int nns[KN];
  int q = blockIdx.x, b = blockIdx.y;
  int r = b * Tq + q;
  int tid = threadIdx.x;
  if (tid < KN) nns[tid] = nn[(size_t)r * KN + tid];
  __syncthreads();

  int w = tid >> 6, lane = tid & 63;
  int mt = w / WPM;
  int nt0 = (w % WPM) * NTW;
  int jl = lane & 15;        // j within tile == A-frag row
  int kg = lane >> 4;        // k-chunk group (8 elems each)
  int j = mt * 16 + jl;
  const float* qwr = Qw + (size_t)r * 256;
  const float* kwr = Kw + ((size_t)b * Tt + nns[j]) * 256;

  f32x4 acc[NTW];
  #pragma unroll
  for (int t = 0; t < NTW; ++t) acc[t] = (f32x4){0.f, 0.f, 0.f, 0.f};

  #pragma unroll
  for (int ks = 0; ks < 8; ++ks) {
    int c0 = ks * 32 + kg * 8;
    float4 qa = *(const float4*)(qwr + c0);
    float4 qb = *(const float4*)(qwr + c0 + 4);
    float4 ka = *(const float4*)(kwr + c0);
    float4 kb = *(const float4*)(kwr + c0 + 4);
    float4 ba = *(const float4*)(b1 + c0);
    float4 bbv = *(const float4*)(b1 + c0 + 4);
    float h[8];
    h[0] = fmaxf(qa.x - ka.x + ba.x, 0.f);
    h[1] = fmaxf(qa.y - ka.y + ba.y, 0.f);
    h[2] = fmaxf(qa.z - ka.z + ba.z, 0.f);
    h[3] = fmaxf(qa.w - ka.w + ba.w, 0.f);
    h[4] = fmaxf(qb.x - kb.x + bbv.x, 0.f);
    h[5] = fmaxf(qb.y - kb.y + bbv.y, 0.f);
    h[6] = fmaxf(qb.z - kb.z + bbv.z, 0.f);
    h[7] = fmaxf(qb.w - kb.w + bbv.w, 0.f);
    bf16x8 ahi, alo;
    #pragma unroll
    for (int i = 0; i < 8; ++i) {
      __bf16 t0 = (__bf16)h[i];
      ahi[i] = t0;
      alo[i] = (__bf16)(h[i] - (float)t0);
    }
    #pragma unroll
    for (int t = 0; t < NTW; ++t) {
      size_t boff = (size_t)((nt0 + t) * 16 + jl) * 256 + c0;
      bf16x8 bhi = *(const bf16x8*)(w2Thi + boff);
      bf16x8 blo = *(const bf16x8*)(w2Tlo + boff);
      acc[t] = __builtin_amdgcn_mfma_f32_16x16x32_bf16(alo, bhi, acc[t], 0, 0, 0);
      acc[t] = __builtin_amdgcn_mfma_f32_16x16x32_bf16(ahi, blo, acc[t], 0, 0, 0);
      acc[t] = __builtin_amdgcn_mfma_f32_16x16x32_bf16(ahi, bhi, acc[t], 0, 0, 0);
    }
  }
  // C/D layout (HW-verified): col = lane&15, row = (lane>>4)*4 + reg
  #pragma unroll
  for (int t = 0; t < NTW; ++t)
    #pragma unroll
    for (int qi = 0; qi < 4; ++qi)
      sim[(mt * 16 + kg * 4 + qi) * LD + (nt0 + t) * 16 + jl] = acc[t][qi];
  __syncthreads();

  // Epilogue: identical math to verified attn2 (softmax over j, V gather)
  int c = tid;
  float bb2 = b2[c];
  const float* vbb = Vb + (size_t)b * Tt * 256;
  float m = -INFINITY;
  #pragma unroll 4
  for (int jj = 0; jj < KN; ++jj)
    m = fmaxf(m, sim[jj * LD + c] + bb2);
  float ssum = 0.f, o = 0.f;
  #pragma unroll 4
  for (int jj = 0; jj < KN; ++jj) {
    float e = expf(sim[jj * LD + c] + bb2 - m);
    ssum += e;
    float vv = vbb[(size_t)nns[jj] * 256 + c];
    o = fmaf(e, vv, o);
  }
  out[(size_t)r * 256 + c] = o / ssum + skip[(size_t)r * 256 + c];
}

// ---------------------------------------------------------------------------
// Final head
// ---------------------------------------------------------------------------
__global__ void gmean_kernel(const float* __restrict__ tok,
                             float* __restrict__ out, int Tt)
{
  int i = blockIdx.x * blockDim.x + threadIdx.x;
  if (i >= BB * CC) return;
  int b = i >> 8;
  int c = i & 255;
  float s = 0.f;
  for (int t = 0; t < Tt; ++t) s += tok[((size_t)b * Tt + t) * 256 + c];
  out[i] = s / (float)Tt;
}

__global__ void embbn_kernel(const float* __restrict__ x,
                             const float* __restrict__ g,
                             const float* __restrict__ bta,
                             float* __restrict__ y)
{
  int e = blockIdx.x * blockDim.x + threadIdx.x;
  if (e >= EE) return;
  float s = 0.f;
  for (int r = 0; r < BB; ++r) s += x[r * EE + e];
  float m = s / (float)BB;
  float vs = 0.f;
  for (int r = 0; r < BB; ++r) {
    float d = x[r * EE + e] - m;
    vs = fmaf(d, d, vs);
  }
  float rs = rsqrtf(vs / (float)BB + 1e-5f);
  for (int r = 0; r < BB; ++r) {
    float val = (x[r * EE + e] - m) * rs * g[e] + bta[e];
    y[r * EE + e] = fmaxf(val, 0.f);
  }
}

__global__ __launch_bounds__(256) void topk_norm_kernel(
    const float* __restrict__ gin, float* __restrict__ out)
{
  int b = blockIdx.x, tid = threadIdx.x, lane = tid & 63, wid = tid >> 6;
  __shared__ float vals[512];
  __shared__ float wv[4];
  __shared__ int wi[4];
  __shared__ float sh;
  float g0 = gin[b * 512 + tid];
  float g1 = gin[b * 512 + 256 + tid];
  vals[tid] = g0;
  vals[256 + tid] = g1;
  __syncthreads();
  for (int it = 0; it < 64; ++it) {
    float v = vals[tid];
    int ix = tid;
    float u = vals[256 + tid];
    if (u > v) { v = u; ix = 256 + tid; }
    #pragma unroll
    for (int off = 32; off > 0; off >>= 1) {
      float ov = __shfl_down(v, off);
      int oi = __shfl_down(ix, off);
      if (ov > v || (ov == v && oi < ix)) { v = ov; ix = oi; }
    }
    if (lane == 0) { wv[wid] = v; wi[wid] = ix; }
    __syncthreads();
    if (tid == 0) {
      float bv = wv[0]; int bi = wi[0];
      for (int w = 1; w < 4; ++w)
        if (wv[w] > bv || (wv[w] == bv && wi[w] < bi)) { bv = wv[w]; bi = wi[w]; }
      vals[bi] = -INFINITY;
      sh = bv;
    }
    __syncthreads();
  }
  float thr = sh;
  float m0 = (g0 >= thr) ? g0 : 0.f;
  float m1 = (g1 >= thr) ? g1 : 0.f;
  float ss = m0 * m0 + m1 * m1;
  #pragma unroll
  for (int off = 32; off > 0; off >>= 1) ss += __shfl_down(ss, off);
  if (lane == 0) wv[wid] = ss;
  __syncthreads();
  if (tid == 0) {
    float t = wv[0] + wv[1] + wv[2] + wv[3];
    sh = fmaxf(sqrtf(t), 1e-12f);
  }
  __syncthreads();
  float n = sh;
  out[b * 512 + tid] = m0 / n;
  out[b * 512 + 256 + tid] = m1 / n;
}

// ---------------------------------------------------------------------------
// Host orchestration
// ---------------------------------------------------------------------------
extern "C" void kernel_launch(void* const* d_in, const int* in_sizes, int n_in,
                              void* d_out, int out_size, void* d_ws, size_t ws_size,
                              hipStream_t stream)
{
  const float* tokens  = (const float*)d_in[0];
  const float* centers = (const float*)d_in[1];
  // d_in[2] = lrfs: dead in the reference
  const float* wq      = (const float*)d_in[3];
  const float* wkv     = (const float*)d_in[4];
  const float* mlp_w1  = (const float*)d_in[5];
  const float* mlp_b1  = (const float*)d_in[6];
  const float* mlp_w2  = (const float*)d_in[7];
  const float* mlp_b2  = (const float*)d_in[8];
  const float* bn1_g   = (const float*)d_in[9];
  const float* bn1_b   = (const float*)d_in[10];
  const float* bn2_g   = (const float*)d_in[11];
  const float* bn2_b   = (const float*)d_in[12];
  const float* att_w1  = (const float*)d_in[13];
  const float* att_b1  = (const float*)d_in[14];
  const float* att_w2  = (const float*)d_in[15];
  const float* att_b2  = (const float*)d_in[16];
  const float* emb_w   = (const float*)d_in[17];
  const float* emb_b   = (const float*)d_in[18];
  const float* embn_g  = (const float*)d_in[19];
  const float* embn_b  = (const float*)d_in[20];
  (void)in_sizes; (void)n_in; (void)out_size; (void)ws_size;

  char* ws = (char*)d_ws;
  size_t off = 0;
  auto alloc = [&](size_t bytes) -> void* {
    void* p = ws + off;
    off += (bytes + 255) & ~(size_t)255;
    return p;
  };
  const size_t tokMax  = (size_t)BB * 512 * CC * 4;   // 8 MB
  const size_t tgtMax  = (size_t)BB * 1024 * CC * 4;  // 16 MB
  float* tokA     = (float*)alloc(tokMax);
  float* tokB     = (float*)alloc(tokMax);
  float* ctrA     = (float*)alloc((size_t)BB * 512 * 3 * 4);
  float* ctrB     = (float*)alloc((size_t)BB * 512 * 3 * 4);
  float* tokq_raw = (float*)alloc(tokMax);
  float* tokq_bn  = (float*)alloc(tokMax);
  float* tokt_bn  = (float*)alloc(tgtMax);
  float* Qw1      = (float*)alloc(tokMax);
  float* Kw1      = (float*)alloc(tgtMax);
  float* Vbuf     = (float*)alloc(tgtMax);
  float* tq1      = (float*)alloc(tokMax);
  float* tqbn     = (float*)alloc(tokMax);
  float* mlph     = (float*)alloc((size_t)BB * 512 * 512 * 4);
  float* WFq      = (float*)alloc((size_t)3 * CC * CC * 4);
  float* WFk      = (float*)alloc((size_t)3 * CC * CC * 4);
  __bf16* w2Thi   = (__bf16*)alloc((size_t)3 * CC * CC * 2);
  __bf16* w2Tlo   = (__bf16*)alloc((size_t)3 * CC * CC * 2);
  int*   rep      = (int*)alloc((size_t)BB * 512 * 4);
  int*   nnb      = (int*)alloc((size_t)BB * 512 * 64 * 4);
  float* bnpart   = (float*)alloc((size_t)64 * 512 * 4);
  float* bnmean   = (float*)alloc(256 * 4);
  float* bnrstd   = (float*)alloc(256 * 4);
  float* gmeanb   = (float*)alloc((size_t)BB * CC * 4);
  float* gembb    = (float*)alloc((size_t)BB * EE * 4);
  float* grelub   = (float*)alloc((size_t)BB * EE * 4);

  const int NC[3] = {512, 256, 128};
  const int NN[3] = {16, 32, 64};

  // One-time weight prep:
  //   WFq_i = wq_i @ att_w1_i ; WFk_i = wkv_i[:, :C] @ att_w1_i
  //   w2T hi/lo = bf16-split transpose of att_w2_i
  for (int i = 0; i < 3; ++i) {
    gemm_kernel<<<dim3(4, 4), 256, 0, stream>>>(
        wq + (size_t)i * CC * CC, CC, att_w1 + (size_t)i * CC * CC, CC,
        nullptr, nullptr, WFq + (size_t)i * CC * CC, CC, CC, CC, 0);
    gemm_kernel<<<dim3(4, 4), 256, 0, stream>>>(
        wkv + (size_t)i * CC * 512, 512, att_w1 + (size_t)i * CC * CC, CC,
        nullptr, nullptr, WFk + (size_t)i * CC * CC, CC, CC, CC, 0);
  }
  split_w2_kernel<<<3 * 65536 / 256, 256, 0, stream>>>(att_w2, w2Thi, w2Tlo);

  const float* cur_tok = tokens;
  const float* cur_ctr = centers;
  int curTt = TT0;

  float* tok_bufs[2] = {tokA, tokB};
  float* ctr_bufs[2] = {ctrA, ctrB};

  for (int i = 0; i < 3; ++i) {
    int Tq = NC[i], Kn = NN[i], Tt = curTt;
    float* ctr_q = ctr_bufs[i & 1];
    float* tok_next = tok_bufs[i & 1];
    int M = BB * Tq;
    int Mt = BB * Tt;

    // FPS (single-wave) + gathers + kNN (index-exact)
    if (Tt == 1024)
      fps_wave_kernel<16><<<BB, 64, 0, stream>>>(cur_ctr, Tt, Tq, rep);
    else if (Tt == 512)
      fps_wave_kernel<8><<<BB, 64, 0, stream>>>(cur_ctr, Tt, Tq, rep);
    else
      fps_wave_kernel<4><<<BB, 64, 0, stream>>>(cur_ctr, Tt, Tq, rep);
    {
      int tot = BB * Tq * 3;
      gather_rows_kernel<<<(tot + 255) / 256, 256, 0, stream>>>(
          cur_ctr, rep, ctr_q, Tq, Tt, 3, tot);
    }
    {
      int tot = M * CC;
      gather_rows_kernel<<<(tot + 255) / 256, 256, 0, stream>>>(
          cur_tok, rep, tokq_raw, Tq, Tt, CC, tot);
    }
    knn_kernel<<<M, 256, 0, stream>>>(ctr_q, cur_ctr, Tq, Tt, Kn, nnb);

    // Optional BN1 over concat(query, target)
    const float* q_src;
    const float* t_src;
    if (i == 0) {
      q_src = tokq_raw;
      t_src = cur_tok;
    } else {
      int R1 = M, R2 = Mt;
      bn_stats_kernel<<<64, 256, 0, stream>>>(tokq_raw, R1, cur_tok, R2, bnpart, 64);
      bn_finalize_kernel<<<1, 256, 0, stream>>>(bnpart, 64, R1 + R2, bnmean, bnrstd);
      {
        int tot = R1 * CC;
        bn_apply_kernel<<<(tot + 255) / 256, 256, 0, stream>>>(
            tokq_raw, tokq_bn, bnmean, bnrstd, bn1_g + i * CC, bn1_b + i * CC, tot);
      }
      {
        int tot = R2 * CC;
        bn_apply_kernel<<<(tot + 255) / 256, 256, 0, stream>>>(
            cur_tok, tokt_bn, bnmean, bnrstd, bn1_g + i * CC, bn1_b + i * CC, tot);
      }
      q_src = tokq_bn;
      t_src = tokt_bn;
    }

    // Projections (folded): Qw1 = q @ (wq@w1); Kw1 = t @ (wkv_K@w1); V = t @ wkv_V
    gemm_kernel<<<dim3(CC / 64, M / 64), 256, 0, stream>>>(
        q_src, CC, WFq + (size_t)i * CC * CC, CC, nullptr, nullptr,
        Qw1, M, CC, CC, 0);
    gemm_kernel<<<dim3(CC / 64, Mt / 64), 256, 0, stream>>>(
        t_src, CC, WFk + (size_t)i * CC * CC, CC, nullptr, nullptr,
        Kw1, Mt, CC, CC, 0);
    gemm_kernel<<<dim3(CC / 64, Mt / 64), 256, 0, stream>>>(
        t_src, CC, wkv + (size_t)i * CC * 512 + CC, 512, nullptr, nullptr,
        Vbuf, Mt, CC, CC, 0);

    // Fused neighborhood attention via MFMA (+ skip)
    if (Kn == 16)
      attn3_kernel<16><<<dim3(Tq, BB), 256, 0, stream>>>(
          Qw1, Kw1, Vbuf, nnb, att_b1 + i * CC,
          w2Thi + (size_t)i * CC * CC, w2Tlo + (size_t)i * CC * CC,
          att_b2 + i * CC, tokq_raw, tq1, Tq, Tt);
    else if (Kn == 32)
      attn3_kernel<32><<<dim3(Tq, BB), 256, 0, stream>>>(
          Qw1, Kw1, Vbuf, nnb, att_b1 + i * CC,
          w2Thi + (size_t)i * CC * CC, w2Tlo + (size_t)i * CC * CC,
          att_b2 + i * CC, tokq_raw, tq1, Tq, Tt);
    else
      attn3_kernel<64><<<dim3(Tq, BB), 256, 0, stream>>>(
          Qw1, Kw1, Vbuf, nnb, att_b1 + i * CC,
          w2Thi + (size_t)i * CC * CC, w2Tlo + (size_t)i * CC * CC,
          att_b2 + i * CC, tokq_raw, tq1, Tq, Tt);

    // BN2 + MLP (+ skip2)
    bn_stats_kernel<<<64, 256, 0, stream>>>(tq1, M, tq1, 0, bnpart, 64);
    bn_finalize_kernel<<<1, 256, 0, stream>>>(bnpart, 64, M, bnmean, bnrstd);
    {
      int tot = M * CC;
      bn_apply_kernel<<<(tot + 255) / 256, 256, 0, stream>>>(
          tq1, tqbn, bnmean, bnrstd, bn2_g + i * CC, bn2_b + i * CC, tot);
    }
    gemm_kernel<<<dim3(512 / 64, M / 64), 256, 0, stream>>>(
        tqbn, CC, mlp_w1 + (size_t)i * CC * 512, 512, mlp_b1 + i * 512, nullptr,
        mlph, M, 512, CC, 1);
    gemm_kernel<<<dim3(CC / 64, M / 64), 256, 0, stream>>>(
        mlph, 512, mlp_w2 + (size_t)i * 512 * CC, CC, mlp_b2 + i * CC, tq1,
        tok_next, M, CC, 512, 0);

    cur_tok = tok_next;
    cur_ctr = ctr_q;
    curTt = Tq;
  }

  // Final head
  gmean_kernel<<<(BB * CC + 255) / 256, 256, 0, stream>>>(cur_tok, gmeanb, curTt);
  gemm_kernel<<<dim3(EE / 64, 1), 256, 0, stream>>>(
      gmeanb, CC, emb_w, EE, emb_b, nullptr, gembb, BB, EE, CC, 0);
  embbn_kernel<<<2, 256, 0, stream>>>(gembb, embn_g, embn_b, grelub);
  topk_norm_kernel<<<BB, 256, 0, stream>>>(grelub, (float*)d_out);
}

// Round 6
// 2148.732 us; speedup vs baseline: 1.9101x; 1.1529x over previous
//
#include <hip/hip_runtime.h>
#include <cstdint>
#include <cmath>

// Problem constants
static constexpr int BB = 16;    // batch
static constexpr int TT0 = 1024; // initial tokens
static constexpr int CC = 256;   // channels
static constexpr int EE = 512;   // embedding

typedef __bf16 bf16x8 __attribute__((ext_vector_type(8)));
typedef float  f32x4  __attribute__((ext_vector_type(4)));

// ---------------------------------------------------------------------------
// FPS, single-wave version (verified round 2): one 64-lane wave per batch.
// ---------------------------------------------------------------------------
template <int NPL>
__global__ __launch_bounds__(64) void fps_wave_kernel(
    const float* __restrict__ ctr, int Tt, int Ksel, int* __restrict__ rep)
{
  __shared__ float4 sp[1024];
  int b = blockIdx.x;
  int lane = threadIdx.x;
  const float* base = ctr + (size_t)b * Tt * 3;
  float x[NPL], y[NPL], z[NPL], d[NPL];
  #pragma unroll
  for (int j = 0; j < NPL; ++j) {
    int idx = lane * NPL + j;
    x[j] = base[idx * 3 + 0];
    y[j] = base[idx * 3 + 1];
    z[j] = base[idx * 3 + 2];
    d[j] = INFINITY;
    sp[idx] = make_float4(x[j], y[j], z[j], 0.f);
  }
  int cur = 0;
  for (int s = 0; s < Ksel; ++s) {
    if (lane == 0) rep[b * Ksel + s] = cur;
    float4 cpt = sp[cur];  // uniform address -> broadcast
    unsigned long long key = 0ull;
    #pragma unroll
    for (int j = 0; j < NPL; ++j) {
      float dx = __fsub_rn(x[j], cpt.x);
      float dy = __fsub_rn(y[j], cpt.y);
      float dz = __fsub_rn(z[j], cpt.z);
      float dist = __fadd_rn(__fadd_rn(__fmul_rn(dx, dx), __fmul_rn(dy, dy)),
                             __fmul_rn(dz, dz));
      float nd = fminf(d[j], dist);
      d[j] = nd;
      unsigned long long kj =
          ((unsigned long long)__float_as_uint(nd) << 32) |
          (unsigned)(0xFFFFFFFFu - (unsigned)(lane * NPL + j));
      key = (kj > key) ? kj : key;
    }
    #pragma unroll
    for (int off = 32; off > 0; off >>= 1) {
      unsigned long long ok = __shfl_xor(key, off);
      key = (ok > key) ? ok : key;
    }
    cur = (int)(0xFFFFFFFFu - (unsigned)(key & 0xFFFFFFFFull));
  }
}

// ---------------------------------------------------------------------------
// kNN (index-exact, verified)
// ---------------------------------------------------------------------------
__global__ __launch_bounds__(256) void knn_kernel(
    const float* __restrict__ cq, const float* __restrict__ ct,
    int Tq, int Tt, int Kn, int* __restrict__ nn)
{
  int r = blockIdx.x;     // b*Tq + q
  int b = r / Tq;
  __shared__ float d2[1024];
  __shared__ float wv[4];
  __shared__ int wi[4];
  int tid = threadIdx.x, lane = tid & 63, wid = tid >> 6;
  float qx = cq[(size_t)r * 3 + 0];
  float qy = cq[(size_t)r * 3 + 1];
  float qz = cq[(size_t)r * 3 + 2];
  float sq = __fadd_rn(__fadd_rn(__fmul_rn(qx, qx), __fmul_rn(qy, qy)),
                       __fmul_rn(qz, qz));
  for (int t = tid; t < Tt; t += 256) {
    const float* tp = ct + ((size_t)b * Tt + t) * 3;
    float tx = tp[0], ty = tp[1], tz = tp[2];
    float st = __fadd_rn(__fadd_rn(__fmul_rn(tx, tx), __fmul_rn(ty, ty)),
                         __fmul_rn(tz, tz));
    float dot = __fadd_rn(__fadd_rn(__fmul_rn(qx, tx), __fmul_rn(qy, ty)),
                          __fmul_rn(qz, tz));
    d2[t] = __fsub_rn(__fadd_rn(sq, st), __fmul_rn(2.0f, dot));
  }
  __syncthreads();
  for (int j = 0; j < Kn; ++j) {
    float v = INFINITY; int ix = 0x7fffffff;
    for (int t = tid; t < Tt; t += 256) {
      float dv = d2[t];
      if (dv < v) { v = dv; ix = t; }
    }
    #pragma unroll
    for (int off = 32; off > 0; off >>= 1) {
      float ov = __shfl_down(v, off);
      int oi = __shfl_down(ix, off);
      if (ov < v || (ov == v && oi < ix)) { v = ov; ix = oi; }
    }
    if (lane == 0) { wv[wid] = v; wi[wid] = ix; }
    __syncthreads();
    if (tid == 0) {
      float bv = wv[0]; int bi = wi[0];
      for (int w = 1; w < 4; ++w)
        if (wv[w] < bv || (wv[w] == bv && wi[w] < bi)) { bv = wv[w]; bi = wi[w]; }
      nn[(size_t)r * Kn + j] = bi;
      d2[bi] = INFINITY;
    }
    __syncthreads();
  }
}

// ---------------------------------------------------------------------------
// Row gather
// ---------------------------------------------------------------------------
__global__ void gather_rows_kernel(
    const float* __restrict__ src, const int* __restrict__ idx,
    float* __restrict__ dst, int Tq, int Tt, int D, int total)
{
  int i = blockIdx.x * blockDim.x + threadIdx.x;
  if (i >= total) return;
  int d = i % D;
  int q = (i / D) % Tq;
  int b = i / (D * Tq);
  int s = idx[b * Tq + q];
  dst[i] = src[((size_t)b * Tt + s) * D + d];
}

// ---------------------------------------------------------------------------
// BatchNorm over rows (axis 0), C = 256 channels.
// ---------------------------------------------------------------------------
__global__ __launch_bounds__(256) void bn_stats_kernel(
    const float* __restrict__ x1, int R1, const float* __restrict__ x2, int R2,
    float* __restrict__ part, int nch)
{
  int c = threadIdx.x;
  int chunk = blockIdx.x;
  int R = R1 + R2;
  int per = (R + nch - 1) / nch;
  int r0 = chunk * per;
  int r1 = min(r0 + per, R);
  float s = 0.f, ss = 0.f;
  for (int r = r0; r < r1; ++r) {
    float v = (r < R1) ? x1[(size_t)r * 256 + c] : x2[(size_t)(r - R1) * 256 + c];
    s += v;
    ss = fmaf(v, v, ss);
  }
  part[(size_t)chunk * 512 + c] = s;
  part[(size_t)chunk * 512 + 256 + c] = ss;
}

__global__ __launch_bounds__(256) void bn_finalize_kernel(
    const float* __restrict__ part, int nch, int R,
    float* __restrict__ mean, float* __restrict__ rstd)
{
  int c = threadIdx.x;
  float s = 0.f, ss = 0.f;
  for (int k = 0; k < nch; ++k) {
    s += part[(size_t)k * 512 + c];
    ss += part[(size_t)k * 512 + 256 + c];
  }
  float m = s / (float)R;
  float v = ss / (float)R - m * m;
  if (v < 0.f) v = 0.f;
  mean[c] = m;
  rstd[c] = rsqrtf(v + 1e-5f);
}

__global__ void bn_apply_kernel(
    const float* __restrict__ x, float* __restrict__ y,
    const float* __restrict__ mean, const float* __restrict__ rstd,
    const float* __restrict__ g, const float* __restrict__ bta, int total)
{
  int i = blockIdx.x * blockDim.x + threadIdx.x;
  if (i >= total) return;
  int c = i & 255;
  y[i] = (x[i] - mean[c]) * rstd[c] * g[c] + bta[c];
}

// ---------------------------------------------------------------------------
// fp32 tiled GEMM (unchanged)
// ---------------------------------------------------------------------------
__global__ __launch_bounds__(256) void gemm_kernel(
    const float* __restrict__ A, int lda,
    const float* __restrict__ W, int ldw,
    const float* __restrict__ bias, const float* __restrict__ resid,
    float* __restrict__ out, int M, int N, int K, int relu)
{
  __shared__ float As[32][68];
  __shared__ float Bs[32][68];
  int bm = blockIdx.y * 64;
  int bn = blockIdx.x * 64;
  int tid = threadIdx.x;
  int tx = tid & 15, ty = tid >> 4;
  int arow = tid >> 3;          // 0..31
  int ak = (tid & 7) * 4;       // 0,4,...,28
  int wk = tid >> 4;            // 0..15
  int wn = (tid & 15) * 4;      // 0..60
  float acc[4][4] = {{0.f}};
  for (int k0 = 0; k0 < K; k0 += 32) {
    #pragma unroll
    for (int h = 0; h < 2; ++h) {
      int row = bm + arow + h * 32;
      float4 a = (row < M)
          ? *(const float4*)&A[(size_t)row * lda + k0 + ak]
          : make_float4(0.f, 0.f, 0.f, 0.f);
      As[ak + 0][arow + h * 32] = a.x;
      As[ak + 1][arow + h * 32] = a.y;
      As[ak + 2][arow + h * 32] = a.z;
      As[ak + 3][arow + h * 32] = a.w;
    }
    #pragma unroll
    for (int h = 0; h < 2; ++h) {
      int krow = k0 + wk + h * 16;
      *(float4*)&Bs[wk + h * 16][wn] =
          *(const float4*)&W[(size_t)krow * ldw + bn + wn];
    }
    __syncthreads();
    #pragma unroll
    for (int k = 0; k < 32; ++k) {
      float4 a = *(const float4*)&As[k][ty * 4];
      float4 b = *(const float4*)&Bs[k][tx * 4];
      float av[4] = {a.x, a.y, a.z, a.w};
      float bv[4] = {b.x, b.y, b.z, b.w};
      #pragma unroll
      for (int i = 0; i < 4; ++i)
        #pragma unroll
        for (int j = 0; j < 4; ++j)
          acc[i][j] = fmaf(av[i], bv[j], acc[i][j]);
    }
    __syncthreads();
  }
  #pragma unroll
  for (int i = 0; i < 4; ++i) {
    int m = bm + ty * 4 + i;
    if (m >= M) continue;
    #pragma unroll
    for (int j = 0; j < 4; ++j) {
      int n = bn + tx * 4 + j;
      float v = acc[i][j];
      if (bias) v += bias[n];
      if (relu) v = fmaxf(v, 0.f);
      if (resid) v += resid[(size_t)m * N + n];
      out[(size_t)m * N + n] = v;
    }
  }
}

// ---------------------------------------------------------------------------
// w2 transpose + bf16 hi/lo split: in w2[3][c][c'] f32 -> out [3][c'][c] bf16
// ---------------------------------------------------------------------------
__global__ __launch_bounds__(256) void split_w2_kernel(
    const float* __restrict__ w2, __bf16* __restrict__ hi,
    __bf16* __restrict__ lo)
{
  int i = blockIdx.x * 256 + threadIdx.x;   // over 3*65536
  int s = i >> 16;
  int e = i & 65535;
  int cp = e >> 8;   // c' (row of transposed)
  int cc = e & 255;  // c
  float v = w2[((size_t)s << 16) + cc * 256 + cp];
  __bf16 h = (__bf16)v;
  hi[i] = h;
  lo[i] = (__bf16)(v - (float)h);
}

// ---------------------------------------------------------------------------
// MFMA attention v4: 128 j-rows per block (G = 128/KN query rows) so the
// w2T hi/lo read (256 KB/block) is amortized over 8 m-tiles instead of 1.
//   h in A-frag registers (hi/lo bf16 split, fragment mapping verified r5),
//   sim = h @ w2 via 3x mfma per (m,n,ks); sim -> LDS [128][260] fp32;
//   epilogue = verified per-channel softmax over j + V gather + skip, per
//   query group g.
// Wave w: all 8 m-tiles x n-tiles [4w, 4w+4). 96 MFMA : 8 B-loads per k-step.
// ---------------------------------------------------------------------------
template <int KN>
__global__ __launch_bounds__(256, 1) void attn4_kernel(
    const float* __restrict__ Qw, const float* __restrict__ Kw,
    const float* __restrict__ Vb, const int* __restrict__ nn,
    const float* __restrict__ b1, const __bf16* __restrict__ w2Thi,
    const __bf16* __restrict__ w2Tlo, const float* __restrict__ b2,
    const float* __restrict__ skip, float* __restrict__ out, int Tq, int Tt)
{
  constexpr int G  = 128 / KN;   // query rows per block
  constexpr int LD = 260;        // 2-way bank alias on C-store = free (m136)
  __shared__ float sim[128 * LD];  // 133 KB (<=160 KB/CU)
  __shared__ int nns[128];
  int r0 = blockIdx.x * G;       // flat query row base (within one batch:
  int b = r0 / Tq;               // G divides Tq for all stages)
  int tid = threadIdx.x;
  if (tid < 128) nns[tid] = nn[(size_t)r0 * KN + tid];
  __syncthreads();

  int w = tid >> 6, lane = tid & 63;
  int jl = lane & 15;        // A-frag row / B-frag col
  int kg = lane >> 4;        // k-chunk group (8 elems)
  int nt0 = w * 4;
  const float* kwb = Kw + (size_t)b * Tt * 256;

  f32x4 acc[8][4];
  #pragma unroll
  for (int m = 0; m < 8; ++m)
    #pragma unroll
    for (int n = 0; n < 4; ++n) acc[m][n] = (f32x4){0.f, 0.f, 0.f, 0.f};

  const float* qp[8];
  const float* kp[8];
  #pragma unroll
  for (int mt = 0; mt < 8; ++mt) {
    int jr = mt * 16 + jl;
    qp[mt] = Qw + (size_t)(r0 + jr / KN) * 256;
    kp[mt] = kwb + (size_t)nns[jr] * 256;
  }

  #pragma unroll
  for (int ks = 0; ks < 8; ++ks) {
    int c0 = ks * 32 + kg * 8;
    float4 b1a = *(const float4*)(b1 + c0);
    float4 b1b = *(const float4*)(b1 + c0 + 4);
    bf16x8 ahi[8], alo[8];
    #pragma unroll
    for (int mt = 0; mt < 8; ++mt) {
      float4 qa = *(const float4*)(qp[mt] + c0);
      float4 qb = *(const float4*)(qp[mt] + c0 + 4);
      float4 ka = *(const float4*)(kp[mt] + c0);
      float4 kb = *(const float4*)(kp[mt] + c0 + 4);
      float h[8];
      h[0] = fmaxf(qa.x - ka.x + b1a.x, 0.f);
      h[1] = fmaxf(qa.y - ka.y + b1a.y, 0.f);
      h[2] = fmaxf(qa.z - ka.z + b1a.z, 0.f);
      h[3] = fmaxf(qa.w - ka.w + b1a.w, 0.f);
      h[4] = fmaxf(qb.x - kb.x + b1b.x, 0.f);
      h[5] = fmaxf(qb.y - kb.y + b1b.y, 0.f);
      h[6] = fmaxf(qb.z - kb.z + b1b.z, 0.f);
      h[7] = fmaxf(qb.w - kb.w + b1b.w, 0.f);
      #pragma unroll
      for (int i = 0; i < 8; ++i) {
        __bf16 t0 = (__bf16)h[i];
        ahi[mt][i] = t0;
        alo[mt][i] = (__bf16)(h[i] - (float)t0);
      }
    }
    #pragma unroll
    for (int t = 0; t < 4; ++t) {
      size_t boff = (size_t)((nt0 + t) * 16 + jl) * 256 + c0;
      bf16x8 bhi = *(const bf16x8*)(w2Thi + boff);
      bf16x8 blo = *(const bf16x8*)(w2Tlo + boff);
      #pragma unroll
      for (int mt = 0; mt < 8; ++mt) {
        acc[mt][t] = __builtin_amdgcn_mfma_f32_16x16x32_bf16(alo[mt], bhi, acc[mt][t], 0, 0, 0);
        acc[mt][t] = __builtin_amdgcn_mfma_f32_16x16x32_bf16(ahi[mt], blo, acc[mt][t], 0, 0, 0);
        acc[mt][t] = __builtin_amdgcn_mfma_f32_16x16x32_bf16(ahi[mt], bhi, acc[mt][t], 0, 0, 0);
      }
    }
  }
  // C/D layout (HW-verified): col = lane&15, row = (lane>>4)*4 + reg
  #pragma unroll
  for (int mt = 0; mt < 8; ++mt)
    #pragma unroll
    for (int t = 0; t < 4; ++t)
      #pragma unroll
      for (int qi = 0; qi < 4; ++qi)
        sim[(mt * 16 + kg * 4 + qi) * LD + (nt0 + t) * 16 + jl] = acc[mt][t][qi];
  __syncthreads();

  // Epilogue (verified math): per channel c, per query group g.
  int c = tid;
  float bb2 = b2[c];
  const float* vbb = Vb + (size_t)b * Tt * 256;
  #pragma unroll
  for (int g = 0; g < G; ++g) {
    int jb = g * KN;
    float m = -INFINITY;
    #pragma unroll 8
    for (int jj = 0; jj < KN; ++jj)
      m = fmaxf(m, sim[(jb + jj) * LD + c] + bb2);
    float ssum = 0.f, o = 0.f;
    #pragma unroll 8
    for (int jj = 0; jj < KN; ++jj) {
      float e = expf(sim[(jb + jj) * LD + c] + bb2 - m);
      ssum += e;
      o = fmaf(e, vbb[(size_t)nns[jb + jj] * 256 + c], o);
    }
    int r = r0 + g;
    out[(size_t)r * 256 + c] = o / ssum + skip[(size_t)r * 256 + c];
  }
}

// ---------------------------------------------------------------------------
// Final head
// ---------------------------------------------------------------------------
__global__ void gmean_kernel(const float* __restrict__ tok,
                             float* __restrict__ out, int Tt)
{
  int i = blockIdx.x * blockDim.x + threadIdx.x;
  if (i >= BB * CC) return;
  int b = i >> 8;
  int c = i & 255;
  float s = 0.f;
  for (int t = 0; t < Tt; ++t) s += tok[((size_t)b * Tt + t) * 256 + c];
  out[i] = s / (float)Tt;
}

__global__ void embbn_kernel(const float* __restrict__ x,
                             const float* __restrict__ g,
                             const float* __restrict__ bta,
                             float* __restrict__ y)
{
  int e = blockIdx.x * blockDim.x + threadIdx.x;
  if (e >= EE) return;
  float s = 0.f;
  for (int r = 0; r < BB; ++r) s += x[r * EE + e];
  float m = s / (float)BB;
  float vs = 0.f;
  for (int r = 0; r < BB; ++r) {
    float d = x[r * EE + e] - m;
    vs = fmaf(d, d, vs);
  }
  float rs = rsqrtf(vs / (float)BB + 1e-5f);
  for (int r = 0; r < BB; ++r) {
    float val = (x[r * EE + e] - m) * rs * g[e] + bta[e];
    y[r * EE + e] = fmaxf(val, 0.f);
  }
}

__global__ __launch_bounds__(256) void topk_norm_kernel(
    const float* __restrict__ gin, float* __restrict__ out)
{
  int b = blockIdx.x, tid = threadIdx.x, lane = tid & 63, wid = tid >> 6;
  __shared__ float vals[512];
  __shared__ float wv[4];
  __shared__ int wi[4];
  __shared__ float sh;
  float g0 = gin[b * 512 + tid];
  float g1 = gin[b * 512 + 256 + tid];
  vals[tid] = g0;
  vals[256 + tid] = g1;
  __syncthreads();
  for (int it = 0; it < 64; ++it) {
    float v = vals[tid];
    int ix = tid;
    float u = vals[256 + tid];
    if (u > v) { v = u; ix = 256 + tid; }
    #pragma unroll
    for (int off = 32; off > 0; off >>= 1) {
      float ov = __shfl_down(v, off);
      int oi = __shfl_down(ix, off);
      if (ov > v || (ov == v && oi < ix)) { v = ov; ix = oi; }
    }
    if (lane == 0) { wv[wid] = v; wi[wid] = ix; }
    __syncthreads();
    if (tid == 0) {
      float bv = wv[0]; int bi = wi[0];
      for (int w = 1; w < 4; ++w)
        if (wv[w] > bv || (wv[w] == bv && wi[w] < bi)) { bv = wv[w]; bi = wi[w]; }
      vals[bi] = -INFINITY;
      sh = bv;
    }
    __syncthreads();
  }
  float thr = sh;
  float m0 = (g0 >= thr) ? g0 : 0.f;
  float m1 = (g1 >= thr) ? g1 : 0.f;
  float ss = m0 * m0 + m1 * m1;
  #pragma unroll
  for (int off = 32; off > 0; off >>= 1) ss += __shfl_down(ss, off);
  if (lane == 0) wv[wid] = ss;
  __syncthreads();
  if (tid == 0) {
    float t = wv[0] + wv[1] + wv[2] + wv[3];
    sh = fmaxf(sqrtf(t), 1e-12f);
  }
  __syncthreads();
  float n = sh;
  out[b * 512 + tid] = m0 / n;
  out[b * 512 + 256 + tid] = m1 / n;
}

// ---------------------------------------------------------------------------
// Host orchestration
// ---------------------------------------------------------------------------
extern "C" void kernel_launch(void* const* d_in, const int* in_sizes, int n_in,
                              void* d_out, int out_size, void* d_ws, size_t ws_size,
                              hipStream_t stream)
{
  const float* tokens  = (const float*)d_in[0];
  const float* centers = (const float*)d_in[1];
  // d_in[2] = lrfs: dead in the reference
  const float* wq      = (const float*)d_in[3];
  const float* wkv     = (const float*)d_in[4];
  const float* mlp_w1  = (const float*)d_in[5];
  const float* mlp_b1  = (const float*)d_in[6];
  const float* mlp_w2  = (const float*)d_in[7];
  const float* mlp_b2  = (const float*)d_in[8];
  const float* bn1_g   = (const float*)d_in[9];
  const float* bn1_b   = (const float*)d_in[10];
  const float* bn2_g   = (const float*)d_in[11];
  const float* bn2_b   = (const float*)d_in[12];
  const float* att_w1  = (const float*)d_in[13];
  const float* att_b1  = (const float*)d_in[14];
  const float* att_w2  = (const float*)d_in[15];
  const float* att_b2  = (const float*)d_in[16];
  const float* emb_w   = (const float*)d_in[17];
  const float* emb_b   = (const float*)d_in[18];
  const float* embn_g  = (const float*)d_in[19];
  const float* embn_b  = (const float*)d_in[20];
  (void)in_sizes; (void)n_in; (void)out_size; (void)ws_size;

  char* ws = (char*)d_ws;
  size_t off = 0;
  auto alloc = [&](size_t bytes) -> void* {
    void* p = ws + off;
    off += (bytes + 255) & ~(size_t)255;
    return p;
  };
  const size_t tokMax  = (size_t)BB * 512 * CC * 4;   // 8 MB
  const size_t tgtMax  = (size_t)BB * 1024 * CC * 4;  // 16 MB
  float* tokA     = (float*)alloc(tokMax);
  float* tokB     = (float*)alloc(tokMax);
  float* ctrA     = (float*)alloc((size_t)BB * 512 * 3 * 4);
  float* ctrB     = (float*)alloc((size_t)BB * 512 * 3 * 4);
  float* tokq_raw = (float*)alloc(tokMax);
  float* tokq_bn  = (float*)alloc(tokMax);
  float* tokt_bn  = (float*)alloc(tgtMax);
  float* Qw1      = (float*)alloc(tokMax);
  float* Kw1      = (float*)alloc(tgtMax);
  float* Vbuf     = (float*)alloc(tgtMax);
  float* tq1      = (float*)alloc(tokMax);
  float* tqbn     = (float*)alloc(tokMax);
  float* mlph     = (float*)alloc((size_t)BB * 512 * 512 * 4);
  float* WFq      = (float*)alloc((size_t)3 * CC * CC * 4);
  float* WFk      = (float*)alloc((size_t)3 * CC * CC * 4);
  __bf16* w2Thi   = (__bf16*)alloc((size_t)3 * CC * CC * 2);
  __bf16* w2Tlo   = (__bf16*)alloc((size_t)3 * CC * CC * 2);
  int*   rep      = (int*)alloc((size_t)BB * 512 * 4);
  int*   nnb      = (int*)alloc((size_t)BB * 512 * 64 * 4);
  float* bnpart   = (float*)alloc((size_t)64 * 512 * 4);
  float* bnmean   = (float*)alloc(256 * 4);
  float* bnrstd   = (float*)alloc(256 * 4);
  float* gmeanb   = (float*)alloc((size_t)BB * CC * 4);
  float* gembb    = (float*)alloc((size_t)BB * EE * 4);
  float* grelub   = (float*)alloc((size_t)BB * EE * 4);

  const int NC[3] = {512, 256, 128};
  const int NN[3] = {16, 32, 64};

  // One-time weight prep:
  //   WFq_i = wq_i @ att_w1_i ; WFk_i = wkv_i[:, :C] @ att_w1_i
  //   w2T hi/lo = bf16-split transpose of att_w2_i
  for (int i = 0; i < 3; ++i) {
    gemm_kernel<<<dim3(4, 4), 256, 0, stream>>>(
        wq + (size_t)i * CC * CC, CC, att_w1 + (size_t)i * CC * CC, CC,
        nullptr, nullptr, WFq + (size_t)i * CC * CC, CC, CC, CC, 0);
    gemm_kernel<<<dim3(4, 4), 256, 0, stream>>>(
        wkv + (size_t)i * CC * 512, 512, att_w1 + (size_t)i * CC * CC, CC,
        nullptr, nullptr, WFk + (size_t)i * CC * CC, CC, CC, CC, 0);
  }
  split_w2_kernel<<<3 * 65536 / 256, 256, 0, stream>>>(att_w2, w2Thi, w2Tlo);

  const float* cur_tok = tokens;
  const float* cur_ctr = centers;
  int curTt = TT0;

  float* tok_bufs[2] = {tokA, tokB};
  float* ctr_bufs[2] = {ctrA, ctrB};

  for (int i = 0; i < 3; ++i) {
    int Tq = NC[i], Kn = NN[i], Tt = curTt;
    float* ctr_q = ctr_bufs[i & 1];
    float* tok_next = tok_bufs[i & 1];
    int M = BB * Tq;
    int Mt = BB * Tt;

    // FPS (single-wave) + gathers + kNN (index-exact)
    if (Tt == 1024)
      fps_wave_kernel<16><<<BB, 64, 0, stream>>>(cur_ctr, Tt, Tq, rep);
    else if (Tt == 512)
      fps_wave_kernel<8><<<BB, 64, 0, stream>>>(cur_ctr, Tt, Tq, rep);
    else
      fps_wave_kernel<4><<<BB, 64, 0, stream>>>(cur_ctr, Tt, Tq, rep);
    {
      int tot = BB * Tq * 3;
      gather_rows_kernel<<<(tot + 255) / 256, 256, 0, stream>>>(
          cur_ctr, rep, ctr_q, Tq, Tt, 3, tot);
    }
    {
      int tot = M * CC;
      gather_rows_kernel<<<(tot + 255) / 256, 256, 0, stream>>>(
          cur_tok, rep, tokq_raw, Tq, Tt, CC, tot);
    }
    knn_kernel<<<M, 256, 0, stream>>>(ctr_q, cur_ctr, Tq, Tt, Kn, nnb);

    // Optional BN1 over concat(query, target)
    const float* q_src;
    const float* t_src;
    if (i == 0) {
      q_src = tokq_raw;
      t_src = cur_tok;
    } else {
      int R1 = M, R2 = Mt;
      bn_stats_kernel<<<64, 256, 0, stream>>>(tokq_raw, R1, cur_tok, R2, bnpart, 64);
      bn_finalize_kernel<<<1, 256, 0, stream>>>(bnpart, 64, R1 + R2, bnmean, bnrstd);
      {
        int tot = R1 * CC;
        bn_apply_kernel<<<(tot + 255) / 256, 256, 0, stream>>>(
            tokq_raw, tokq_bn, bnmean, bnrstd, bn1_g + i * CC, bn1_b + i * CC, tot);
      }
      {
        int tot = R2 * CC;
        bn_apply_kernel<<<(tot + 255) / 256, 256, 0, stream>>>(
            cur_tok, tokt_bn, bnmean, bnrstd, bn1_g + i * CC, bn1_b + i * CC, tot);
      }
      q_src = tokq_bn;
      t_src = tokt_bn;
    }

    // Projections (folded): Qw1 = q @ (wq@w1); Kw1 = t @ (wkv_K@w1); V = t @ wkv_V
    gemm_kernel<<<dim3(CC / 64, M / 64), 256, 0, stream>>>(
        q_src, CC, WFq + (size_t)i * CC * CC, CC, nullptr, nullptr,
        Qw1, M, CC, CC, 0);
    gemm_kernel<<<dim3(CC / 64, Mt / 64), 256, 0, stream>>>(
        t_src, CC, WFk + (size_t)i * CC * CC, CC, nullptr, nullptr,
        Kw1, Mt, CC, CC, 0);
    gemm_kernel<<<dim3(CC / 64, Mt / 64), 256, 0, stream>>>(
        t_src, CC, wkv + (size_t)i * CC * 512 + CC, 512, nullptr, nullptr,
        Vbuf, Mt, CC, CC, 0);

    // Fused neighborhood attention via MFMA, 128 rows/block (+ skip)
    if (Kn == 16)
      attn4_kernel<16><<<dim3(M / 8), 256, 0, stream>>>(
          Qw1, Kw1, Vbuf, nnb, att_b1 + i * CC,
          w2Thi + (size_t)i * CC * CC, w2Tlo + (size_t)i * CC * CC,
          att_b2 + i * CC, tokq_raw, tq1, Tq, Tt);
    else if (Kn == 32)
      attn4_kernel<32><<<dim3(M / 4), 256, 0, stream>>>(
          Qw1, Kw1, Vbuf, nnb, att_b1 + i * CC,
          w2Thi + (size_t)i * CC * CC, w2Tlo + (size_t)i * CC * CC,
          att_b2 + i * CC, tokq_raw, tq1, Tq, Tt);
    else
      attn4_kernel<64><<<dim3(M / 2), 256, 0, stream>>>(
          Qw1, Kw1, Vbuf, nnb, att_b1 + i * CC,
          w2Thi + (size_t)i * CC * CC, w2Tlo + (size_t)i * CC * CC,
          att_b2 + i * CC, tokq_raw, tq1, Tq, Tt);

    // BN2 + MLP (+ skip2)
    bn_stats_kernel<<<64, 256, 0, stream>>>(tq1, M, tq1, 0, bnpart, 64);
    bn_finalize_kernel<<<1, 256, 0, stream>>>(bnpart, 64, M, bnmean, bnrstd);
    {
      int tot = M * CC;
      bn_apply_kernel<<<(tot + 255) / 256, 256, 0, stream>>>(
          tq1, tqbn, bnmean, bnrstd, bn2_g + i * CC, bn2_b + i * CC, tot);
    }
    gemm_kernel<<<dim3(512 / 64, M / 64), 256, 0, stream>>>(
        tqbn, CC, mlp_w1 + (size_t)i * CC * 512, 512, mlp_b1 + i * 512, nullptr,
        mlph, M, 512, CC, 1);
    gemm_kernel<<<dim3(CC / 64, M / 64), 256, 0, stream>>>(
        mlph, 512, mlp_w2 + (size_t)i * 512 * CC, CC, mlp_b2 + i * CC, tq1,
        tok_next, M, CC, 512, 0);

    cur_tok = tok_next;
    cur_ctr = ctr_q;
    curTt = Tq;
  }

  // Final head
  gmean_kernel<<<(BB * CC + 255) / 256, 256, 0, stream>>>(cur_tok, gmeanb, curTt);
  gemm_kernel<<<dim3(EE / 64, 1), 256, 0, stream>>>(
      gmeanb, CC, emb_w, EE, emb_b, nullptr, gembb, BB, EE, CC, 0);
  embbn_kernel<<<2, 256, 0, stream>>>(gembb, embn_g, embn_b, grelub);
  topk_norm_kernel<<<BB, 256, 0, stream>>>(grelub, (float*)d_out);
}